// Round 1
// baseline (9564.725 us; speedup 1.0000x reference)
//
#include <hip/hip_runtime.h>
#include <hip/hip_bf16.h>
#include <math.h>

// Problem constants (match reference)
#define B 64
#define T 19
#define S 80
#define V 32000
#define E 256
#define U 1024
#define U3 (3*U)        // 3072
#define KXM (E+U)       // 1280

// ---------------------------------------------------------------------------
// Generic fp32 SGEMM: C[M, N] = A[M, K] @ W[K, N] (+ bias[n])
//   - M tiled by 64 via blockIdx.y (row0 = blockIdx.y*64)
//   - N tiled by 64 via blockIdx.x
//   - BK = 16, 256 threads, each thread computes 4x4
//   - A rows contiguous with leading dim K; C leading dim ldc
// ---------------------------------------------------------------------------
__global__ __launch_bounds__(256) void sgemm_tile(
    const float* __restrict__ A, const float* __restrict__ W,
    const float* __restrict__ bias, float* __restrict__ C,
    int N, int K, int ldc)
{
    __shared__ float As[16][64];     // [kk][m]
    __shared__ float Ws[16][64];     // [kk][n]

    const int tid = threadIdx.x;
    const int tx = tid & 15;         // col group (0..15) -> 4 cols
    const int ty = tid >> 4;         // row group (0..15) -> 4 rows
    const int bn = blockIdx.x * 64;
    const int row0 = blockIdx.y * 64;

    float acc[4][4] = {};

    const int lm = tid >> 2;           // 0..63
    const int lk = (tid & 3) * 4;      // 0,4,8,12
    const int wk = tid >> 6;           // 0..3
    const int wn = tid & 63;           // 0..63

    for (int k0 = 0; k0 < K; k0 += 16) {
        // Stage A tile: As[kk][m] = A[row0+m][k0+kk]
        float4 av = *(const float4*)(A + (size_t)(row0 + lm) * K + k0 + lk);
        As[lk + 0][lm] = av.x;
        As[lk + 1][lm] = av.y;
        As[lk + 2][lm] = av.z;
        As[lk + 3][lm] = av.w;
        // Stage W tile: Ws[kk][n] = W[k0+kk][bn+n]
        #pragma unroll
        for (int i = 0; i < 4; i++) {
            Ws[wk + i * 4][wn] = W[(size_t)(k0 + wk + i * 4) * N + bn + wn];
        }
        __syncthreads();
        #pragma unroll
        for (int kk = 0; kk < 16; kk++) {
            const float4 a4 = *(const float4*)&As[kk][ty * 4];
            const float4 w4 = *(const float4*)&Ws[kk][tx * 4];
            const float a[4] = {a4.x, a4.y, a4.z, a4.w};
            const float w[4] = {w4.x, w4.y, w4.z, w4.w};
            #pragma unroll
            for (int i = 0; i < 4; i++)
                #pragma unroll
                for (int j = 0; j < 4; j++)
                    acc[i][j] += a[i] * w[j];
        }
        __syncthreads();
    }

    #pragma unroll
    for (int i = 0; i < 4; i++) {
        const int m = row0 + ty * 4 + i;
        #pragma unroll
        for (int j = 0; j < 4; j++) {
            const int n = bn + tx * 4 + j;
            float v = acc[i][j] + (bias ? bias[n] : 0.f);
            C[(size_t)m * ldc + n] = v;
        }
    }
}

// ---------------------------------------------------------------------------
// Build cell_in[b, 0:256] = embedding[x[b,t]][:], cell_in[b, 256:1280] = attnv[b][:]
// ---------------------------------------------------------------------------
__global__ __launch_bounds__(256) void cellin_kernel(
    const int* __restrict__ x, int t, const float* __restrict__ emb,
    const float* __restrict__ attnv, float* __restrict__ cellin)
{
    int idx = blockIdx.x * 256 + threadIdx.x;   // B*KXM
    int b = idx / KXM, c = idx % KXM;
    float v;
    if (c < E) {
        int tok = x[b * T + t];
        v = emb[(size_t)tok * E + c];
    } else {
        v = attnv[b * U + (c - E)];
    }
    cellin[idx] = v;
}

// ---------------------------------------------------------------------------
// GRU gates (reset_after=True, order [z, r, h]); h updated in place.
// ---------------------------------------------------------------------------
__global__ __launch_bounds__(256) void gates_kernel(
    const float* __restrict__ xm, const float* __restrict__ hm,
    float* __restrict__ h)
{
    int idx = blockIdx.x * 256 + threadIdx.x;   // B*U
    int b = idx >> 10, u = idx & (U - 1);
    const float* xr = xm + (size_t)b * U3;
    const float* hr = hm + (size_t)b * U3;
    float z = 1.f / (1.f + expf(-(xr[u] + hr[u])));
    float r = 1.f / (1.f + expf(-(xr[U + u] + hr[U + u])));
    float hh = tanhf(xr[2 * U + u] + r * hr[2 * U + u]);
    float hv = h[idx];
    h[idx] = z * hv + (1.f - z) * hh;
}

// ---------------------------------------------------------------------------
// Attention per batch b (one block): score = h . keys[s], softmax, context.
// ---------------------------------------------------------------------------
__global__ __launch_bounds__(256) void attention_kernel(
    const float* __restrict__ h, const float* __restrict__ keys,
    const float* __restrict__ memory, float* __restrict__ ctx)
{
    const int b = blockIdx.x;
    __shared__ float hs[U];
    __shared__ float sc[S];

    for (int i = threadIdx.x; i < U; i += 256) hs[i] = h[(size_t)b * U + i];
    __syncthreads();

    const int wave = threadIdx.x >> 6;
    const int lane = threadIdx.x & 63;
    for (int s = wave; s < S; s += 4) {
        const float* krow = keys + ((size_t)b * S + s) * U;
        float p = 0.f;
        for (int u = lane; u < U; u += 64) p += krow[u] * hs[u];
        #pragma unroll
        for (int off = 32; off > 0; off >>= 1) p += __shfl_down(p, off);
        if (lane == 0) sc[s] = p;
    }
    __syncthreads();
    if (threadIdx.x == 0) {
        float m = -1e30f;
        for (int s = 0; s < S; s++) m = fmaxf(m, sc[s]);
        float sum = 0.f;
        for (int s = 0; s < S; s++) { float e = expf(sc[s] - m); sc[s] = e; sum += e; }
        float inv = 1.f / sum;
        for (int s = 0; s < S; s++) sc[s] *= inv;
    }
    __syncthreads();
    for (int u = threadIdx.x; u < U; u += 256) {
        float acc = 0.f;
        for (int s = 0; s < S; s++)
            acc += sc[s] * memory[((size_t)b * S + s) * U + u];
        ctx[(size_t)b * U + u] = acc;
    }
}

// ---------------------------------------------------------------------------
// cat2[b, 0:U] = h[b], cat2[b, U:2U] = ctx[b]
// ---------------------------------------------------------------------------
__global__ __launch_bounds__(256) void cat2_kernel(
    const float* __restrict__ h, const float* __restrict__ ctx,
    float* __restrict__ cat2)
{
    int idx = blockIdx.x * 256 + threadIdx.x;   // B*2U
    int b = idx / (2 * U), c = idx % (2 * U);
    cat2[idx] = (c < U) ? h[b * U + c] : ctx[b * U + (c - U)];
}

// ---------------------------------------------------------------------------
extern "C" void kernel_launch(void* const* d_in, const int* in_sizes, int n_in,
                              void* d_out, int out_size, void* d_ws, size_t ws_size,
                              hipStream_t stream)
{
    const int*   x      = (const int*)  d_in[0];
    const float* enc    = (const float*)d_in[1];
    const float* memory = (const float*)d_in[2];
    const float* emb    = (const float*)d_in[3];
    const float* gk     = (const float*)d_in[4];
    const float* grk    = (const float*)d_in[5];
    const float* gb     = (const float*)d_in[6];
    const float* memW   = (const float*)d_in[7];
    const float* attnW  = (const float*)d_in[8];
    const float* fcW    = (const float*)d_in[9];
    const float* fcb    = (const float*)d_in[10];
    float* out = (float*)d_out;
    float* ws  = (float*)d_ws;

    // Workspace layout (floats)
    float* keys   = ws;                       size_t off = (size_t)B * S * U;
    float* h      = ws + off;                 off += B * U;
    float* attnv  = ws + off;                 off += B * U;
    float* cellin = ws + off;                 off += B * KXM;
    float* cat2   = ws + off;                 off += B * 2 * U;
    float* xm     = ws + off;                 off += B * U3;
    float* hm     = ws + off;                 off += B * U3;
    float* ctx    = ws + off;                 off += B * U;

    // init: h = enc_state, attnv = 0
    hipMemcpyAsync(h, enc, (size_t)B * U * sizeof(float),
                   hipMemcpyDeviceToDevice, stream);
    hipMemsetAsync(attnv, 0, (size_t)B * U * sizeof(float), stream);

    dim3 blk(256);

    // keys = memory @ mem_W   ([B*S, U] @ [U, U])
    sgemm_tile<<<dim3(U / 64, (B * S) / 64), blk, 0, stream>>>(
        memory, memW, nullptr, keys, U, U, U);

    for (int t = 0; t < T; t++) {
        cellin_kernel<<<(B * KXM) / 256, blk, 0, stream>>>(x, t, emb, attnv, cellin);
        // xm = cell_in @ gru_kernel + b_in
        sgemm_tile<<<dim3(U3 / 64, 1), blk, 0, stream>>>(
            cellin, gk, gb, xm, U3, KXM, U3);
        // hm = h @ gru_rec_kernel + b_rec
        sgemm_tile<<<dim3(U3 / 64, 1), blk, 0, stream>>>(
            h, grk, gb + U3, hm, U3, U, U3);
        // gates -> h (in place)
        gates_kernel<<<(B * U) / 256, blk, 0, stream>>>(xm, hm, h);
        // attention -> ctx
        attention_kernel<<<B, blk, 0, stream>>>(h, keys, memory, ctx);
        // cat2 = [h, ctx]
        cat2_kernel<<<(B * 2 * U) / 256, blk, 0, stream>>>(h, ctx, cat2);
        // attnv = cat2 @ attn_W
        sgemm_tile<<<dim3(U / 64, 1), blk, 0, stream>>>(
            cat2, attnW, nullptr, attnv, U, 2 * U, U);
        // logits[:, t, :] = attnv @ fc_W + fc_b
        sgemm_tile<<<dim3(V / 64, 1), blk, 0, stream>>>(
            attnv, fcW, fcb, out + (size_t)t * V, V, U, T * V);
    }
}

// Round 4
// 6542.293 us; speedup vs baseline: 1.4620x; 1.4620x over previous
//
#include <hip/hip_runtime.h>
#include <hip/hip_bf16.h>
#include <math.h>

#define B 64
#define T 19
#define S 80
#define V 32000
#define E 256
#define U 1024
#define U3 (3*U)        // 3072
#define KXM (E+U)       // 1280

typedef unsigned short ushortT;
typedef __attribute__((ext_vector_type(8))) __bf16 bf16x8;
typedef __attribute__((ext_vector_type(4))) float f32x4;

__device__ __forceinline__ ushortT f2bf(float f) {
    unsigned int u = __float_as_uint(f);
    u = (u + 0x7FFF + ((u >> 16) & 1)) >> 16;   // RNE
    return (ushortT)u;
}
__device__ __forceinline__ float bf2f(ushortT u) {
    return __uint_as_float(((unsigned int)u) << 16);
}
// exact 3-way split: v = hi + mid + lo + O(2^-24 * v)
__device__ __forceinline__ void split3(float v, ushortT& hi, ushortT& mid, ushortT& lo) {
    hi = f2bf(v);
    float r1 = v - bf2f(hi);     // exact
    mid = f2bf(r1);
    float r2 = r1 - bf2f(mid);   // exact
    lo = f2bf(r2);
}

// ---------------------------------------------------------------------------
// High-precision MFMA GEMM (bf16x3 split, 6 MFMA/k-chunk): fp32-class error.
// C[M,N] = A[M,K] @ W[K,N] (+bias), A & W fp32 row-major, C fp32.
// Tile 64x64, 4 waves each owning a 16-col strip; A staged (hi/mid/lo) in LDS.
// ---------------------------------------------------------------------------
__global__ __launch_bounds__(256) void gemm_split6(
    const float* __restrict__ A, const float* __restrict__ W,
    const float* __restrict__ bias, float* __restrict__ C,
    int N, int K, int ldc)
{
    const int tid = threadIdx.x;
    const int lane = tid & 63;
    const int wave = tid >> 6;
    const int row0 = blockIdx.y * 64;
    const int ntile = blockIdx.x * 4 + wave;
    const int col = ntile * 16 + (lane & 15);
    const int kfrag = (lane >> 4) * 8;
    const int KC = K >> 5;

    __shared__ __align__(16) ushortT Ahi[2048];
    __shared__ __align__(16) ushortT Amid[2048];
    __shared__ __align__(16) ushortT Alo[2048];

    f32x4 acc[4] = {};

    const int arow_idx = row0 + (tid >> 6) * 16 + (tid & 15);
    const int kgof = ((tid >> 4) & 3) * 8;

    for (int kc = 0; kc < KC; kc++) {
        // ---- stage A chunk split into hi/mid/lo fragments ----
        const float* ar = A + (size_t)arow_idx * K + kc * 32 + kgof;
        float av[8];
        *(float4*)(av)     = *(const float4*)(ar);
        *(float4*)(av + 4) = *(const float4*)(ar + 4);
        ushortT thi[8], tmi[8], tlo[8];
        #pragma unroll
        for (int i = 0; i < 8; i++) split3(av[i], thi[i], tmi[i], tlo[i]);
        ((uint4*)Ahi)[tid]  = *(const uint4*)thi;
        ((uint4*)Amid)[tid] = *(const uint4*)tmi;
        ((uint4*)Alo)[tid]  = *(const uint4*)tlo;

        // ---- W fragment (8 rows x this col) split in registers ----
        const float* wp = W + (size_t)(kc * 32 + kfrag) * N + col;
        ushortT whi[8], wmi[8], wlo[8];
        #pragma unroll
        for (int i = 0; i < 8; i++) {
            float wv = wp[(size_t)i * N];
            split3(wv, whi[i], wmi[i], wlo[i]);
        }
        bf16x8 bh = *(const bf16x8*)whi;
        bf16x8 bm = *(const bf16x8*)wmi;
        bf16x8 bl = *(const bf16x8*)wlo;

        __syncthreads();
        #pragma unroll
        for (int mi = 0; mi < 4; mi++) {
            bf16x8 ah = *(const bf16x8*)(Ahi  + (mi * 64 + lane) * 8);
            bf16x8 am = *(const bf16x8*)(Amid + (mi * 64 + lane) * 8);
            bf16x8 al = *(const bf16x8*)(Alo  + (mi * 64 + lane) * 8);
            acc[mi] = __builtin_amdgcn_mfma_f32_16x16x32_bf16(ah, bh, acc[mi], 0, 0, 0);
            acc[mi] = __builtin_amdgcn_mfma_f32_16x16x32_bf16(am, bh, acc[mi], 0, 0, 0);
            acc[mi] = __builtin_amdgcn_mfma_f32_16x16x32_bf16(ah, bm, acc[mi], 0, 0, 0);
            acc[mi] = __builtin_amdgcn_mfma_f32_16x16x32_bf16(am, bm, acc[mi], 0, 0, 0);
            acc[mi] = __builtin_amdgcn_mfma_f32_16x16x32_bf16(al, bh, acc[mi], 0, 0, 0);
            acc[mi] = __builtin_amdgcn_mfma_f32_16x16x32_bf16(ah, bl, acc[mi], 0, 0, 0);
        }
        __syncthreads();
    }

    const float bv = bias ? bias[col] : 0.f;
    #pragma unroll
    for (int mi = 0; mi < 4; mi++) {
        #pragma unroll
        for (int r = 0; r < 4; r++) {
            int m = row0 + mi * 16 + (lane >> 4) * 4 + r;
            C[(size_t)m * ldc + col] = acc[mi][r] + bv;
        }
    }
}

// ---------------------------------------------------------------------------
// fc weight pack: fp32 [K][N] -> bf16 fragment order (proven equivalent R2==R3)
// ---------------------------------------------------------------------------
__global__ __launch_bounds__(256) void pack_w(
    const float* __restrict__ W, ushortT* __restrict__ Wp, int N, int K)
{
    int idx = blockIdx.x * 256 + threadIdx.x;
    int lane = idx & 63;
    int t = idx >> 6;
    int KC = K >> 5;
    int ntile = t / KC, kc = t - ntile * KC;
    int col = ntile * 16 + (lane & 15);
    int krow = kc * 32 + (lane >> 4) * 8;
    ushortT tmp[8];
    #pragma unroll
    for (int i = 0; i < 8; i++)
        tmp[i] = f2bf(W[(size_t)(krow + i) * N + col]);
    *(uint4*)(Wp + (size_t)idx * 8) = *(uint4*)tmp;
}

// ---------------------------------------------------------------------------
// fc GEMM: logits = A(fp32, inline->bf16) @ Wp(packed bf16) + bias. Output-only
// path: single-bf16 error (~0.013) is fine and carries no feedback.
// ---------------------------------------------------------------------------
__global__ __launch_bounds__(256) void gemm_fc(
    const float* __restrict__ A, const ushortT* __restrict__ Wp,
    const float* __restrict__ bias, float* __restrict__ C,
    int N, int K, int ldc)
{
    const int tid = threadIdx.x;
    const int lane = tid & 63;
    const int wave = tid >> 6;
    const int ntile = blockIdx.x * 4 + wave;
    const int col = ntile * 16 + (lane & 15);
    const int KC = K >> 5;

    __shared__ __align__(16) ushortT As[2048];

    f32x4 acc[4] = {};
    const int arow_idx = (tid >> 6) * 16 + (tid & 15);
    const int kgof = ((tid >> 4) & 3) * 8;

    for (int kc = 0; kc < KC; kc++) {
        const float* ar = A + (size_t)arow_idx * K + kc * 32 + kgof;
        float4 f0 = *(const float4*)(ar);
        float4 f1 = *(const float4*)(ar + 4);
        ushortT tmp[8] = { f2bf(f0.x), f2bf(f0.y), f2bf(f0.z), f2bf(f0.w),
                           f2bf(f1.x), f2bf(f1.y), f2bf(f1.z), f2bf(f1.w) };
        ((uint4*)As)[tid] = *(const uint4*)tmp;
        bf16x8 b = *(const bf16x8*)(Wp + (((size_t)ntile * KC + kc) * 64 + lane) * 8);
        __syncthreads();
        #pragma unroll
        for (int mi = 0; mi < 4; mi++) {
            bf16x8 a = *(const bf16x8*)(As + (mi * 64 + lane) * 8);
            acc[mi] = __builtin_amdgcn_mfma_f32_16x16x32_bf16(a, b, acc[mi], 0, 0, 0);
        }
        __syncthreads();
    }

    const float bv = bias[col];
    #pragma unroll
    for (int mi = 0; mi < 4; mi++) {
        #pragma unroll
        for (int r = 0; r < 4; r++) {
            int m = mi * 16 + (lane >> 4) * 4 + r;
            C[(size_t)m * ldc + col] = acc[mi][r] + bv;
        }
    }
}

// ---------------------------------------------------------------------------
// fp32 elementwise kernels (round-1 proven logic)
// ---------------------------------------------------------------------------
__global__ __launch_bounds__(256) void init_kernel(
    const float* __restrict__ enc, float* __restrict__ h, float* __restrict__ attnv)
{
    int i = blockIdx.x * 256 + threadIdx.x;
    h[i] = enc[i];
    attnv[i] = 0.f;
}

__global__ __launch_bounds__(256) void cellin_kernel(
    const int* __restrict__ x, int t, const float* __restrict__ emb,
    const float* __restrict__ attnv, float* __restrict__ cellin)
{
    int idx = blockIdx.x * 256 + threadIdx.x;   // B*KXM
    int b = idx / KXM, c = idx - b * KXM;
    float v;
    if (c < E) {
        int tok = x[b * T + t];
        v = emb[(size_t)tok * E + c];
    } else {
        v = attnv[b * U + (c - E)];
    }
    cellin[idx] = v;
}

__global__ __launch_bounds__(256) void gates_kernel(
    const float* __restrict__ xm, const float* __restrict__ hm,
    float* __restrict__ h)
{
    int idx = blockIdx.x * 256 + threadIdx.x;   // B*U
    int b = idx >> 10, u = idx & (U - 1);
    const float* xr = xm + (size_t)b * U3;
    const float* hr = hm + (size_t)b * U3;
    float z = 1.f / (1.f + expf(-(xr[u] + hr[u])));
    float r = 1.f / (1.f + expf(-(xr[U + u] + hr[U + u])));
    float hh = tanhf(xr[2 * U + u] + r * hr[2 * U + u]);
    h[idx] = z * h[idx] + (1.f - z) * hh;
}

// scores[b,s] = h[b] . keys[b,s] — one wave per (b,s), all fp32
__global__ __launch_bounds__(256) void scores_kernel(
    const float* __restrict__ h, const float* __restrict__ keys,
    float* __restrict__ scores)
{
    int gw = blockIdx.x * 4 + (threadIdx.x >> 6);
    int lane = threadIdx.x & 63;
    int b = gw / S, s = gw - b * S;
    const float* kr = keys + ((size_t)b * S + s) * U;
    const float* hr = h + (size_t)b * U;
    float acc = 0.f;
    #pragma unroll
    for (int c = 0; c < 4; c++) {
        int off = c * 256 + lane * 4;
        float4 kv = *(const float4*)(kr + off);
        float4 hv = *(const float4*)(hr + off);
        acc += kv.x * hv.x + kv.y * hv.y + kv.z * hv.z + kv.w * hv.w;
    }
    #pragma unroll
    for (int off = 32; off > 0; off >>= 1) acc += __shfl_down(acc, off);
    if (lane == 0) scores[gw] = acc;
}

// softmax over S + context; grid (B, U/256)
__global__ __launch_bounds__(256) void context_kernel(
    const float* __restrict__ scores, const float* __restrict__ memory,
    float* __restrict__ ctx)
{
    const int b = blockIdx.x;
    const int u = blockIdx.y * 256 + threadIdx.x;
    __shared__ float p[S];
    __shared__ float pn[S];
    if (threadIdx.x < S) p[threadIdx.x] = scores[b * S + threadIdx.x];
    __syncthreads();
    float m = -1e30f;
    #pragma unroll 8
    for (int s = 0; s < S; s++) m = fmaxf(m, p[s]);
    float sum = 0.f;
    #pragma unroll 8
    for (int s = 0; s < S; s++) sum += expf(p[s] - m);
    if (threadIdx.x < S) pn[threadIdx.x] = expf(p[threadIdx.x] - m) / sum;
    __syncthreads();
    float acc = 0.f;
    #pragma unroll 8
    for (int s = 0; s < S; s++)
        acc += pn[s] * memory[((size_t)b * S + s) * U + u];
    ctx[(size_t)b * U + u] = acc;
}

__global__ __launch_bounds__(256) void cat2_kernel(
    const float* __restrict__ h, const float* __restrict__ ctx,
    float* __restrict__ cat2)
{
    int idx = blockIdx.x * 256 + threadIdx.x;   // B*2U
    int b = idx >> 11, c = idx & (2 * U - 1);
    cat2[idx] = (c < U) ? h[b * U + c] : ctx[b * U + (c - U)];
}

// ---------------------------------------------------------------------------
extern "C" void kernel_launch(void* const* d_in, const int* in_sizes, int n_in,
                              void* d_out, int out_size, void* d_ws, size_t ws_size,
                              hipStream_t stream)
{
    const int*   x      = (const int*)  d_in[0];
    const float* enc    = (const float*)d_in[1];
    const float* memory = (const float*)d_in[2];
    const float* emb    = (const float*)d_in[3];
    const float* gk     = (const float*)d_in[4];
    const float* grk    = (const float*)d_in[5];
    const float* gb     = (const float*)d_in[6];
    const float* memW   = (const float*)d_in[7];
    const float* attnW  = (const float*)d_in[8];
    const float* fcW    = (const float*)d_in[9];
    const float* fcb    = (const float*)d_in[10];
    float* out = (float*)d_out;

    char* p = (char*)d_ws;
    auto alloc = [&](size_t bytes) { char* r = p; p += (bytes + 255) & ~(size_t)255; return r; };
    ushortT* fcWp   = (ushortT*)alloc((size_t)U * V * 2);      // 65.5 MB
    float*   keys   = (float*)  alloc((size_t)B * S * U * 4);  // 21 MB
    float*   h      = (float*)  alloc((size_t)B * U * 4);
    float*   attnv  = (float*)  alloc((size_t)B * U * 4);
    float*   cellin = (float*)  alloc((size_t)B * KXM * 4);
    float*   cat2   = (float*)  alloc((size_t)B * 2 * U * 4);
    float*   xm     = (float*)  alloc((size_t)B * U3 * 4);
    float*   hm     = (float*)  alloc((size_t)B * U3 * 4);
    float*   ctx    = (float*)  alloc((size_t)B * U * 4);
    float*   scores = (float*)  alloc((size_t)B * S * 4);

    dim3 blk(256);

    pack_w<<<(size_t)U * V / 8 / 256, blk, 0, stream>>>(fcW, fcWp, V, U);
    init_kernel<<<B * U / 256, blk, 0, stream>>>(enc, h, attnv);

    // keys = memory @ mem_W  (fp32-class precision)
    gemm_split6<<<dim3(U / 64, B * S / 64), blk, 0, stream>>>(
        memory, memW, nullptr, keys, U, U, U);

    for (int t = 0; t < T; t++) {
        cellin_kernel<<<B * KXM / 256, blk, 0, stream>>>(x, t, emb, attnv, cellin);
        gemm_split6<<<dim3(U3 / 64, 1), blk, 0, stream>>>(
            cellin, gk, gb, xm, U3, KXM, U3);
        gemm_split6<<<dim3(U3 / 64, 1), blk, 0, stream>>>(
            h, grk, gb + U3, hm, U3, U, U3);
        gates_kernel<<<B * U / 256, blk, 0, stream>>>(xm, hm, h);
        scores_kernel<<<B * S / 4, blk, 0, stream>>>(h, keys, scores);
        context_kernel<<<dim3(B, U / 256), blk, 0, stream>>>(scores, memory, ctx);
        cat2_kernel<<<B * 2 * U / 256, blk, 0, stream>>>(h, ctx, cat2);
        gemm_split6<<<dim3(U / 64, 1), blk, 0, stream>>>(
            cat2, attnW, nullptr, attnv, U, 2 * U, U);
        gemm_fc<<<dim3(V / 64, 1), blk, 0, stream>>>(
            attnv, fcWp, fcb, out + (size_t)t * V, V, U, T * V);
    }
}

// Round 5
// 2270.977 us; speedup vs baseline: 4.2117x; 2.8808x over previous
//
#include <hip/hip_runtime.h>
#include <hip/hip_bf16.h>
#include <math.h>

#define B 64
#define T 19
#define S 80
#define V 32000
#define E 256
#define U 1024
#define U3 (3*U)        // 3072
#define KXM (E+U)       // 1280

typedef unsigned short ushortT;
typedef __attribute__((ext_vector_type(8))) __bf16 bf16x8;
typedef __attribute__((ext_vector_type(4))) float f32x4;

__device__ __forceinline__ ushortT f2bf(float f) {
    unsigned int u = __float_as_uint(f);
    u = (u + 0x7FFF + ((u >> 16) & 1)) >> 16;   // RNE
    return (ushortT)u;
}
__device__ __forceinline__ float bf2f(ushortT u) {
    return __uint_as_float(((unsigned int)u) << 16);
}
__device__ __forceinline__ void split3(float v, ushortT& hi, ushortT& mid, ushortT& lo) {
    hi = f2bf(v);
    float r1 = v - bf2f(hi);
    mid = f2bf(r1);
    float r2 = r1 - bf2f(mid);
    lo = f2bf(r2);
}

// ---------------------------------------------------------------------------
// split6 GEMM with K-split: Cpart[ks] = A[64, lda] (cols kc range) @ W chunk.
// grid (N/64, SPLITS). M fixed = 64. Partials summed by the consumer.
// ---------------------------------------------------------------------------
__global__ __launch_bounds__(256) void gemm6_ks(
    const float* __restrict__ A, const float* __restrict__ W,
    float* __restrict__ Cpart, int N, int lda, int nkc)
{
    const int tid = threadIdx.x;
    const int lane = tid & 63;
    const int wave = tid >> 6;
    const int ks = blockIdx.y;
    const int ntile = blockIdx.x * 4 + wave;
    const int col = ntile * 16 + (lane & 15);
    const int kfrag = (lane >> 4) * 8;

    __shared__ __align__(16) ushortT Ahi[2048];
    __shared__ __align__(16) ushortT Amid[2048];
    __shared__ __align__(16) ushortT Alo[2048];

    f32x4 acc[4] = {};
    const int arow_idx = (tid >> 6) * 16 + (tid & 15);
    const int kgof = ((tid >> 4) & 3) * 8;

    for (int c = 0; c < nkc; c++) {
        const int kc = ks * nkc + c;
        const float* ar = A + (size_t)arow_idx * lda + kc * 32 + kgof;
        float av[8];
        *(float4*)(av)     = *(const float4*)(ar);
        *(float4*)(av + 4) = *(const float4*)(ar + 4);
        ushortT thi[8], tmi[8], tlo[8];
        #pragma unroll
        for (int i = 0; i < 8; i++) split3(av[i], thi[i], tmi[i], tlo[i]);
        ((uint4*)Ahi)[tid]  = *(const uint4*)thi;
        ((uint4*)Amid)[tid] = *(const uint4*)tmi;
        ((uint4*)Alo)[tid]  = *(const uint4*)tlo;

        const float* wp = W + (size_t)(kc * 32 + kfrag) * N + col;
        ushortT whi[8], wmi[8], wlo[8];
        #pragma unroll
        for (int i = 0; i < 8; i++) {
            float wv = wp[(size_t)i * N];
            split3(wv, whi[i], wmi[i], wlo[i]);
        }
        bf16x8 bh = *(const bf16x8*)whi;
        bf16x8 bm = *(const bf16x8*)wmi;
        bf16x8 bl = *(const bf16x8*)wlo;

        __syncthreads();
        #pragma unroll
        for (int mi = 0; mi < 4; mi++) {
            bf16x8 ah = *(const bf16x8*)(Ahi  + (mi * 64 + lane) * 8);
            bf16x8 am = *(const bf16x8*)(Amid + (mi * 64 + lane) * 8);
            bf16x8 al = *(const bf16x8*)(Alo  + (mi * 64 + lane) * 8);
            acc[mi] = __builtin_amdgcn_mfma_f32_16x16x32_bf16(ah, bh, acc[mi], 0, 0, 0);
            acc[mi] = __builtin_amdgcn_mfma_f32_16x16x32_bf16(am, bh, acc[mi], 0, 0, 0);
            acc[mi] = __builtin_amdgcn_mfma_f32_16x16x32_bf16(ah, bm, acc[mi], 0, 0, 0);
            acc[mi] = __builtin_amdgcn_mfma_f32_16x16x32_bf16(am, bm, acc[mi], 0, 0, 0);
            acc[mi] = __builtin_amdgcn_mfma_f32_16x16x32_bf16(al, bh, acc[mi], 0, 0, 0);
            acc[mi] = __builtin_amdgcn_mfma_f32_16x16x32_bf16(ah, bl, acc[mi], 0, 0, 0);
        }
        __syncthreads();
    }

    float* cp = Cpart + (size_t)ks * 64 * N;
    #pragma unroll
    for (int mi = 0; mi < 4; mi++) {
        #pragma unroll
        for (int r = 0; r < 4; r++) {
            int m = mi * 16 + (lane >> 4) * 4 + r;
            cp[(size_t)m * N + col] = acc[mi][r];
        }
    }
}

// ---------------------------------------------------------------------------
// xe[t] = emb[x[:,t]] @ gk[0:256,:]   grid (U3/64, T); gathered A rows.
// ---------------------------------------------------------------------------
__global__ __launch_bounds__(256) void gemm_xe(
    const int* __restrict__ x, const float* __restrict__ emb,
    const float* __restrict__ gk, float* __restrict__ xe)
{
    const int tid = threadIdx.x;
    const int lane = tid & 63;
    const int wave = tid >> 6;
    const int t = blockIdx.y;
    const int ntile = blockIdx.x * 4 + wave;
    const int col = ntile * 16 + (lane & 15);
    const int kfrag = (lane >> 4) * 8;

    __shared__ __align__(16) ushortT Ahi[2048];
    __shared__ __align__(16) ushortT Amid[2048];
    __shared__ __align__(16) ushortT Alo[2048];

    f32x4 acc[4] = {};
    const int b = (tid >> 6) * 16 + (tid & 15);      // A row = batch index
    const int tok = x[b * T + t];
    const int kgof = ((tid >> 4) & 3) * 8;

    for (int kc = 0; kc < E / 32; kc++) {
        const float* ar = emb + (size_t)tok * E + kc * 32 + kgof;
        float av[8];
        *(float4*)(av)     = *(const float4*)(ar);
        *(float4*)(av + 4) = *(const float4*)(ar + 4);
        ushortT thi[8], tmi[8], tlo[8];
        #pragma unroll
        for (int i = 0; i < 8; i++) split3(av[i], thi[i], tmi[i], tlo[i]);
        ((uint4*)Ahi)[tid]  = *(const uint4*)thi;
        ((uint4*)Amid)[tid] = *(const uint4*)tmi;
        ((uint4*)Alo)[tid]  = *(const uint4*)tlo;

        const float* wp = gk + (size_t)(kc * 32 + kfrag) * U3 + col;
        ushortT whi[8], wmi[8], wlo[8];
        #pragma unroll
        for (int i = 0; i < 8; i++) {
            float wv = wp[(size_t)i * U3];
            split3(wv, whi[i], wmi[i], wlo[i]);
        }
        bf16x8 bh = *(const bf16x8*)whi;
        bf16x8 bm = *(const bf16x8*)wmi;
        bf16x8 bl = *(const bf16x8*)wlo;

        __syncthreads();
        #pragma unroll
        for (int mi = 0; mi < 4; mi++) {
            bf16x8 ah = *(const bf16x8*)(Ahi  + (mi * 64 + lane) * 8);
            bf16x8 am = *(const bf16x8*)(Amid + (mi * 64 + lane) * 8);
            bf16x8 al = *(const bf16x8*)(Alo  + (mi * 64 + lane) * 8);
            acc[mi] = __builtin_amdgcn_mfma_f32_16x16x32_bf16(ah, bh, acc[mi], 0, 0, 0);
            acc[mi] = __builtin_amdgcn_mfma_f32_16x16x32_bf16(am, bh, acc[mi], 0, 0, 0);
            acc[mi] = __builtin_amdgcn_mfma_f32_16x16x32_bf16(ah, bm, acc[mi], 0, 0, 0);
            acc[mi] = __builtin_amdgcn_mfma_f32_16x16x32_bf16(am, bm, acc[mi], 0, 0, 0);
            acc[mi] = __builtin_amdgcn_mfma_f32_16x16x32_bf16(al, bh, acc[mi], 0, 0, 0);
            acc[mi] = __builtin_amdgcn_mfma_f32_16x16x32_bf16(ah, bl, acc[mi], 0, 0, 0);
        }
        __syncthreads();
    }

    #pragma unroll
    for (int mi = 0; mi < 4; mi++) {
        #pragma unroll
        for (int r = 0; r < 4; r++) {
            int m = mi * 16 + (lane >> 4) * 4 + r;
            xe[((size_t)t * 64 + m) * U3 + col] = acc[mi][r];
        }
    }
}

// ---------------------------------------------------------------------------
// keys GEMM (R4's gemm_split6, unchanged): C = A @ W, M tiled by blockIdx.y.
// ---------------------------------------------------------------------------
__global__ __launch_bounds__(256) void gemm_split6(
    const float* __restrict__ A, const float* __restrict__ W,
    float* __restrict__ C, int N, int K, int ldc)
{
    const int tid = threadIdx.x;
    const int lane = tid & 63;
    const int wave = tid >> 6;
    const int row0 = blockIdx.y * 64;
    const int ntile = blockIdx.x * 4 + wave;
    const int col = ntile * 16 + (lane & 15);
    const int kfrag = (lane >> 4) * 8;
    const int KC = K >> 5;

    __shared__ __align__(16) ushortT Ahi[2048];
    __shared__ __align__(16) ushortT Amid[2048];
    __shared__ __align__(16) ushortT Alo[2048];

    f32x4 acc[4] = {};
    const int arow_idx = row0 + (tid >> 6) * 16 + (tid & 15);
    const int kgof = ((tid >> 4) & 3) * 8;

    for (int kc = 0; kc < KC; kc++) {
        const float* ar = A + (size_t)arow_idx * K + kc * 32 + kgof;
        float av[8];
        *(float4*)(av)     = *(const float4*)(ar);
        *(float4*)(av + 4) = *(const float4*)(ar + 4);
        ushortT thi[8], tmi[8], tlo[8];
        #pragma unroll
        for (int i = 0; i < 8; i++) split3(av[i], thi[i], tmi[i], tlo[i]);
        ((uint4*)Ahi)[tid]  = *(const uint4*)thi;
        ((uint4*)Amid)[tid] = *(const uint4*)tmi;
        ((uint4*)Alo)[tid]  = *(const uint4*)tlo;

        const float* wp = W + (size_t)(kc * 32 + kfrag) * N + col;
        ushortT whi[8], wmi[8], wlo[8];
        #pragma unroll
        for (int i = 0; i < 8; i++) {
            float wv = wp[(size_t)i * N];
            split3(wv, whi[i], wmi[i], wlo[i]);
        }
        bf16x8 bh = *(const bf16x8*)whi;
        bf16x8 bm = *(const bf16x8*)wmi;
        bf16x8 bl = *(const bf16x8*)wlo;

        __syncthreads();
        #pragma unroll
        for (int mi = 0; mi < 4; mi++) {
            bf16x8 ah = *(const bf16x8*)(Ahi  + (mi * 64 + lane) * 8);
            bf16x8 am = *(const bf16x8*)(Amid + (mi * 64 + lane) * 8);
            bf16x8 al = *(const bf16x8*)(Alo  + (mi * 64 + lane) * 8);
            acc[mi] = __builtin_amdgcn_mfma_f32_16x16x32_bf16(ah, bh, acc[mi], 0, 0, 0);
            acc[mi] = __builtin_amdgcn_mfma_f32_16x16x32_bf16(am, bh, acc[mi], 0, 0, 0);
            acc[mi] = __builtin_amdgcn_mfma_f32_16x16x32_bf16(ah, bm, acc[mi], 0, 0, 0);
            acc[mi] = __builtin_amdgcn_mfma_f32_16x16x32_bf16(am, bm, acc[mi], 0, 0, 0);
            acc[mi] = __builtin_amdgcn_mfma_f32_16x16x32_bf16(al, bh, acc[mi], 0, 0, 0);
            acc[mi] = __builtin_amdgcn_mfma_f32_16x16x32_bf16(ah, bl, acc[mi], 0, 0, 0);
        }
        __syncthreads();
    }

    #pragma unroll
    for (int mi = 0; mi < 4; mi++) {
        #pragma unroll
        for (int r = 0; r < 4; r++) {
            int m = row0 + mi * 16 + (lane >> 4) * 4 + r;
            C[(size_t)m * ldc + col] = acc[mi][r];
        }
    }
}

// ---------------------------------------------------------------------------
// fc pack + fc GEMM (R4, unchanged)
// ---------------------------------------------------------------------------
__global__ __launch_bounds__(256) void pack_w(
    const float* __restrict__ W, ushortT* __restrict__ Wp, int N, int K)
{
    int idx = blockIdx.x * 256 + threadIdx.x;
    int lane = idx & 63;
    int t = idx >> 6;
    int KC = K >> 5;
    int ntile = t / KC, kc = t - ntile * KC;
    int col = ntile * 16 + (lane & 15);
    int krow = kc * 32 + (lane >> 4) * 8;
    ushortT tmp[8];
    #pragma unroll
    for (int i = 0; i < 8; i++)
        tmp[i] = f2bf(W[(size_t)(krow + i) * N + col]);
    *(uint4*)(Wp + (size_t)idx * 8) = *(uint4*)tmp;
}

__global__ __launch_bounds__(256) void gemm_fc(
    const float* __restrict__ A, const ushortT* __restrict__ Wp,
    const float* __restrict__ bias, float* __restrict__ C,
    int N, int K, int ldc)
{
    const int tid = threadIdx.x;
    const int lane = tid & 63;
    const int wave = tid >> 6;
    const int ntile = blockIdx.x * 4 + wave;
    const int col = ntile * 16 + (lane & 15);
    const int KC = K >> 5;

    __shared__ __align__(16) ushortT As[2048];

    f32x4 acc[4] = {};
    const int arow_idx = (tid >> 6) * 16 + (tid & 15);
    const int kgof = ((tid >> 4) & 3) * 8;

    for (int kc = 0; kc < KC; kc++) {
        const float* ar = A + (size_t)arow_idx * K + kc * 32 + kgof;
        float4 f0 = *(const float4*)(ar);
        float4 f1 = *(const float4*)(ar + 4);
        ushortT tmp[8] = { f2bf(f0.x), f2bf(f0.y), f2bf(f0.z), f2bf(f0.w),
                           f2bf(f1.x), f2bf(f1.y), f2bf(f1.z), f2bf(f1.w) };
        ((uint4*)As)[tid] = *(const uint4*)tmp;
        bf16x8 b = *(const bf16x8*)(Wp + (((size_t)ntile * KC + kc) * 64 + lane) * 8);
        __syncthreads();
        #pragma unroll
        for (int mi = 0; mi < 4; mi++) {
            bf16x8 a = *(const bf16x8*)(As + (mi * 64 + lane) * 8);
            acc[mi] = __builtin_amdgcn_mfma_f32_16x16x32_bf16(a, b, acc[mi], 0, 0, 0);
        }
        __syncthreads();
    }

    const float bv = bias[col];
    #pragma unroll
    for (int mi = 0; mi < 4; mi++) {
        #pragma unroll
        for (int r = 0; r < 4; r++) {
            int m = mi * 16 + (lane >> 4) * 4 + r;
            C[(size_t)m * ldc + col] = acc[mi][r] + bv;
        }
    }
}

// ---------------------------------------------------------------------------
// GRU gates from partials: xm = xe[t] + sum4(xm_part) + b_in,
//                          hm = sum4(hm_part) + b_rec
// ---------------------------------------------------------------------------
__global__ __launch_bounds__(256) void gates2(
    const float* __restrict__ xe_t, const float* __restrict__ xm_part,
    const float* __restrict__ hm_part, const float* __restrict__ gb,
    float* __restrict__ h, int use_xm)
{
    int idx = blockIdx.x * 256 + threadIdx.x;   // B*U
    int b = idx >> 10, u = idx & (U - 1);
    float xv[3], hv[3];
    #pragma unroll
    for (int g = 0; g < 3; g++) {
        int j = g * U + u;
        float xs = xe_t[(size_t)b * U3 + j] + gb[j];
        float hs = gb[U3 + j];
        if (use_xm) {
            #pragma unroll
            for (int p = 0; p < 4; p++)
                xs += xm_part[((size_t)p * 64 + b) * U3 + j];
        }
        #pragma unroll
        for (int p = 0; p < 4; p++)
            hs += hm_part[((size_t)p * 64 + b) * U3 + j];
        xv[g] = xs; hv[g] = hs;
    }
    float z = 1.f / (1.f + expf(-(xv[0] + hv[0])));
    float r = 1.f / (1.f + expf(-(xv[1] + hv[1])));
    float hh = tanhf(xv[2] + r * hv[2]);
    h[idx] = z * h[idx] + (1.f - z) * hh;
}

// scores[b,s] = h[b] . keys[b,s] — one wave per (b,s)
__global__ __launch_bounds__(256) void scores_kernel(
    const float* __restrict__ h, const float* __restrict__ keys,
    float* __restrict__ scores)
{
    int gw = blockIdx.x * 4 + (threadIdx.x >> 6);
    int lane = threadIdx.x & 63;
    int b = gw / S, s = gw - b * S;
    const float* kr = keys + ((size_t)b * S + s) * U;
    const float* hr = h + (size_t)b * U;
    float acc = 0.f;
    #pragma unroll
    for (int c = 0; c < 4; c++) {
        int off = c * 256 + lane * 4;
        float4 kv = *(const float4*)(kr + off);
        float4 hv = *(const float4*)(hr + off);
        acc += kv.x * hv.x + kv.y * hv.y + kv.z * hv.z + kv.w * hv.w;
    }
    #pragma unroll
    for (int off = 32; off > 0; off >>= 1) acc += __shfl_down(acc, off);
    if (lane == 0) scores[gw] = acc;
}

// softmax + context + concat:  cat2[b] = [h[b], ctx[b]]; grid (B, U/256)
__global__ __launch_bounds__(256) void ctxcat_kernel(
    const float* __restrict__ scores, const float* __restrict__ memory,
    const float* __restrict__ h, float* __restrict__ cat2)
{
    const int b = blockIdx.x;
    const int u = blockIdx.y * 256 + threadIdx.x;
    __shared__ float p[S];
    __shared__ float pn[S];
    if (threadIdx.x < S) p[threadIdx.x] = scores[b * S + threadIdx.x];
    __syncthreads();
    float m = -1e30f;
    #pragma unroll 8
    for (int s = 0; s < S; s++) m = fmaxf(m, p[s]);
    float sum = 0.f;
    #pragma unroll 8
    for (int s = 0; s < S; s++) sum += expf(p[s] - m);
    if (threadIdx.x < S) pn[threadIdx.x] = expf(p[threadIdx.x] - m) / sum;
    __syncthreads();
    float acc = 0.f;
    #pragma unroll 8
    for (int s = 0; s < S; s++)
        acc += pn[s] * memory[((size_t)b * S + s) * U + u];
    cat2[(size_t)b * 2 * U + u] = h[(size_t)b * U + u];
    cat2[(size_t)b * 2 * U + U + u] = acc;
}

// attnv = sum8(attn_part)
__global__ __launch_bounds__(256) void reduce_attnv(
    const float* __restrict__ attn_part, float* __restrict__ attnv)
{
    int idx = blockIdx.x * 256 + threadIdx.x;   // B*U
    float s = 0.f;
    #pragma unroll
    for (int p = 0; p < 8; p++) s += attn_part[(size_t)p * B * U + idx];
    attnv[idx] = s;
}

// ---------------------------------------------------------------------------
extern "C" void kernel_launch(void* const* d_in, const int* in_sizes, int n_in,
                              void* d_out, int out_size, void* d_ws, size_t ws_size,
                              hipStream_t stream)
{
    const int*   x      = (const int*)  d_in[0];
    const float* enc    = (const float*)d_in[1];
    const float* memory = (const float*)d_in[2];
    const float* emb    = (const float*)d_in[3];
    const float* gk     = (const float*)d_in[4];
    const float* grk    = (const float*)d_in[5];
    const float* gb     = (const float*)d_in[6];
    const float* memW   = (const float*)d_in[7];
    const float* attnW  = (const float*)d_in[8];
    const float* fcW    = (const float*)d_in[9];
    const float* fcb    = (const float*)d_in[10];
    float* out = (float*)d_out;

    char* p = (char*)d_ws;
    auto alloc = [&](size_t bytes) { char* r = p; p += (bytes + 255) & ~(size_t)255; return r; };
    ushortT* fcWp     = (ushortT*)alloc((size_t)U * V * 2);        // 65.5 MB
    float*   keys     = (float*)  alloc((size_t)B * S * U * 4);    // 21 MB
    float*   xe       = (float*)  alloc((size_t)T * B * U3 * 4);   // 14.9 MB
    float*   xm_part  = (float*)  alloc((size_t)4 * B * U3 * 4);   // 3.1 MB
    float*   hm_part  = (float*)  alloc((size_t)4 * B * U3 * 4);   // 3.1 MB
    float*   attn_part= (float*)  alloc((size_t)8 * B * U * 4);    // 2.1 MB
    float*   h        = (float*)  alloc((size_t)B * U * 4);
    float*   attnv    = (float*)  alloc((size_t)B * U * 4);
    float*   cat2     = (float*)  alloc((size_t)B * 2 * U * 4);
    float*   scores   = (float*)  alloc((size_t)B * S * 4);

    dim3 blk(256);

    pack_w<<<(size_t)U * V / 8 / 256, blk, 0, stream>>>(fcW, fcWp, V, U);
    hipMemcpyAsync(h, enc, (size_t)B * U * sizeof(float),
                   hipMemcpyDeviceToDevice, stream);

    // xe[t] = emb_t @ gk_top for all t (hoisted out of the loop)
    gemm_xe<<<dim3(U3 / 64, T), blk, 0, stream>>>(x, emb, gk, xe);

    // keys = memory @ mem_W
    gemm_split6<<<dim3(U / 64, B * S / 64), blk, 0, stream>>>(
        memory, memW, keys, U, U, U);

    const float* gk_bot = gk + (size_t)E * U3;   // rows 256..1279

    for (int t = 0; t < T; t++) {
        if (t > 0) {
            // xm_part = attnv @ gk_bot (K=1024, split 4)
            gemm6_ks<<<dim3(U3 / 64, 4), blk, 0, stream>>>(
                attnv, gk_bot, xm_part, U3, U, 8);
        }
        // hm_part = h @ grk (K=1024, split 4)
        gemm6_ks<<<dim3(U3 / 64, 4), blk, 0, stream>>>(
            h, grk, hm_part, U3, U, 8);
        gates2<<<B * U / 256, blk, 0, stream>>>(
            xe + (size_t)t * B * U3, xm_part, hm_part, gb, h, t > 0 ? 1 : 0);
        scores_kernel<<<B * S / 4, blk, 0, stream>>>(h, keys, scores);
        ctxcat_kernel<<<dim3(B, U / 256), blk, 0, stream>>>(scores, memory, h, cat2);
        // attn_part = cat2 @ attn_W (K=2048, split 8)
        gemm6_ks<<<dim3(U / 64, 8), blk, 0, stream>>>(
            cat2, attnW, attn_part, U, 2 * U, 8);
        reduce_attnv<<<B * U / 256, blk, 0, stream>>>(attn_part, attnv);
        gemm_fc<<<dim3(V / 64, 1), blk, 0, stream>>>(
            attnv, fcWp, fcb, out + (size_t)t * V, V, U, T * V);
    }
}

// Round 7
// 1521.995 us; speedup vs baseline: 6.2843x; 1.4921x over previous
//
#include <hip/hip_runtime.h>
#include <hip/hip_bf16.h>
#include <math.h>

#define B 64
#define T 19
#define S 80
#define V 32000
#define E 256
#define U 1024
#define U3 (3*U)        // 3072
#define KXM (E+U)       // 1280

typedef unsigned short ushortT;
typedef __attribute__((ext_vector_type(8))) __bf16 bf16x8;
typedef __attribute__((ext_vector_type(4))) float f32x4;

__device__ __forceinline__ ushortT f2bf(float f) {
    unsigned int u = __float_as_uint(f);
    u = (u + 0x7FFF + ((u >> 16) & 1)) >> 16;   // RNE
    return (ushortT)u;
}
__device__ __forceinline__ float bf2f(ushortT u) {
    return __uint_as_float(((unsigned int)u) << 16);
}
__device__ __forceinline__ void split3(float v, ushortT& hi, ushortT& mid, ushortT& lo) {
    hi = f2bf(v);
    float r1 = v - bf2f(hi);
    mid = f2bf(r1);
    float r2 = r1 - bf2f(mid);
    lo = f2bf(r2);
}

// ---------------------------------------------------------------------------
// Pre-split weight pack: W fp32 [K][N] -> 3 bf16 planes (hi/mid/lo), each in
// MFMA fragment order: plane[((ntile*KC + kc)*64 + lane)*8 + i]
// ---------------------------------------------------------------------------
__global__ __launch_bounds__(256) void pack_w3(
    const float* __restrict__ W, ushortT* __restrict__ Wp, int N, int K)
{
    int idx = blockIdx.x * 256 + threadIdx.x;
    int lane = idx & 63;
    int t = idx >> 6;
    int KC = K >> 5;
    int ntile = t / KC, kc = t - ntile * KC;
    int col = ntile * 16 + (lane & 15);
    int krow = kc * 32 + (lane >> 4) * 8;
    ushortT hi[8], mi[8], lo[8];
    #pragma unroll
    for (int i = 0; i < 8; i++)
        split3(W[(size_t)(krow + i) * N + col], hi[i], mi[i], lo[i]);
    size_t ps = (size_t)K * N;
    *(uint4*)(Wp + (size_t)idx * 8)          = *(uint4*)hi;
    *(uint4*)(Wp + ps + (size_t)idx * 8)     = *(uint4*)mi;
    *(uint4*)(Wp + 2 * ps + (size_t)idx * 8) = *(uint4*)lo;
}

// fc pack (single bf16, proven)
__global__ __launch_bounds__(256) void pack_w(
    const float* __restrict__ W, ushortT* __restrict__ Wp, int N, int K)
{
    int idx = blockIdx.x * 256 + threadIdx.x;
    int lane = idx & 63;
    int t = idx >> 6;
    int KC = K >> 5;
    int ntile = t / KC, kc = t - ntile * KC;
    int col = ntile * 16 + (lane & 15);
    int krow = kc * 32 + (lane >> 4) * 8;
    ushortT tmp[8];
    #pragma unroll
    for (int i = 0; i < 8; i++)
        tmp[i] = f2bf(W[(size_t)(krow + i) * N + col]);
    *(uint4*)(Wp + (size_t)idx * 8) = *(uint4*)tmp;
}

// ---------------------------------------------------------------------------
// Unified per-step split6 GEMM with K-split and 2-job fusion (blockIdx.z).
// ---------------------------------------------------------------------------
struct GemmJob {
    const float*   A;      // [64, lda] fp32
    const float*   W;      // fp32 [Kfull][N] (fallback)
    const ushortT* Wp;     // 3-plane packed (presplit)
    unsigned long long ps; // plane stride (elems)
    int kc_base;           // kc offset within packed W
    int KCtot;             // packed W total KC (addressing)
    float* Cpart;          // [splits][64][N]
    int lda;
};

template<bool PRESPLIT>
__global__ __launch_bounds__(256) void gemm6_ks2(
    GemmJob j0, GemmJob j1, int N, int nkc)
{
    const int tid = threadIdx.x;
    const int lane = tid & 63;
    const int wave = tid >> 6;
    const GemmJob J = blockIdx.z ? j1 : j0;
    const int ks = blockIdx.y;
    const int ntile = blockIdx.x * 4 + wave;
    const int col = ntile * 16 + (lane & 15);
    const int kfrag = (lane >> 4) * 8;

    __shared__ __align__(16) ushortT Ahi[2048];
    __shared__ __align__(16) ushortT Amid[2048];
    __shared__ __align__(16) ushortT Alo[2048];

    f32x4 acc[4] = {};
    const int arow = (tid >> 6) * 16 + (tid & 15);
    const int kgof = ((tid >> 4) & 3) * 8;

    for (int c = 0; c < nkc; c++) {
        const int kc = ks * nkc + c;
        const float* ar = J.A + (size_t)arow * J.lda + kc * 32 + kgof;
        float av[8];
        *(float4*)(av)     = *(const float4*)(ar);
        *(float4*)(av + 4) = *(const float4*)(ar + 4);
        ushortT thi[8], tmi[8], tlo[8];
        #pragma unroll
        for (int i = 0; i < 8; i++) split3(av[i], thi[i], tmi[i], tlo[i]);
        ((uint4*)Ahi)[tid]  = *(const uint4*)thi;
        ((uint4*)Amid)[tid] = *(const uint4*)tmi;
        ((uint4*)Alo)[tid]  = *(const uint4*)tlo;

        bf16x8 bh, bm, bl;
        if constexpr (PRESPLIT) {
            size_t fi = (((size_t)ntile * J.KCtot + (J.kc_base + kc)) * 64 + lane) * 8;
            bh = *(const bf16x8*)(J.Wp + fi);
            bm = *(const bf16x8*)(J.Wp + J.ps + fi);
            bl = *(const bf16x8*)(J.Wp + 2 * J.ps + fi);
        } else {
            const float* wp = J.W + (size_t)((J.kc_base + kc) * 32 + kfrag) * N + col;
            ushortT whi[8], wmi[8], wlo[8];
            #pragma unroll
            for (int i = 0; i < 8; i++)
                split3(wp[(size_t)i * N], whi[i], wmi[i], wlo[i]);
            bh = *(const bf16x8*)whi;
            bm = *(const bf16x8*)wmi;
            bl = *(const bf16x8*)wlo;
        }

        __syncthreads();
        #pragma unroll
        for (int mi = 0; mi < 4; mi++) {
            bf16x8 ah = *(const bf16x8*)(Ahi  + (mi * 64 + lane) * 8);
            bf16x8 am = *(const bf16x8*)(Amid + (mi * 64 + lane) * 8);
            bf16x8 al = *(const bf16x8*)(Alo  + (mi * 64 + lane) * 8);
            acc[mi] = __builtin_amdgcn_mfma_f32_16x16x32_bf16(ah, bh, acc[mi], 0, 0, 0);
            acc[mi] = __builtin_amdgcn_mfma_f32_16x16x32_bf16(am, bh, acc[mi], 0, 0, 0);
            acc[mi] = __builtin_amdgcn_mfma_f32_16x16x32_bf16(ah, bm, acc[mi], 0, 0, 0);
            acc[mi] = __builtin_amdgcn_mfma_f32_16x16x32_bf16(am, bm, acc[mi], 0, 0, 0);
            acc[mi] = __builtin_amdgcn_mfma_f32_16x16x32_bf16(al, bh, acc[mi], 0, 0, 0);
            acc[mi] = __builtin_amdgcn_mfma_f32_16x16x32_bf16(ah, bl, acc[mi], 0, 0, 0);
        }
        __syncthreads();
    }

    float* cp = J.Cpart + (size_t)ks * 64 * N;
    #pragma unroll
    for (int mi = 0; mi < 4; mi++) {
        #pragma unroll
        for (int r = 0; r < 4; r++) {
            int m = mi * 16 + (lane >> 4) * 4 + r;
            cp[(size_t)m * N + col] = acc[mi][r];
        }
    }
}

// ---------------------------------------------------------------------------
// keys = memory @ mem_W: 2 n-tiles per wave, grid (U/128, B*S/64).
// ---------------------------------------------------------------------------
template<bool PRESPLIT>
__global__ __launch_bounds__(256) void gemm_keys(
    const float* __restrict__ A, const float* __restrict__ W,
    const ushortT* __restrict__ Wp, float* __restrict__ C)
{
    const int tid = threadIdx.x;
    const int lane = tid & 63;
    const int wave = tid >> 6;
    const int row0 = blockIdx.y * 64;
    const int nt0 = blockIdx.x * 8 + wave * 2;
    const int col0 = nt0 * 16 + (lane & 15);
    const int kfrag = (lane >> 4) * 8;

    __shared__ __align__(16) ushortT Ahi[2048];
    __shared__ __align__(16) ushortT Amid[2048];
    __shared__ __align__(16) ushortT Alo[2048];

    f32x4 acc[2][4] = {};
    const int arow = row0 + (tid >> 6) * 16 + (tid & 15);
    const int kgof = ((tid >> 4) & 3) * 8;
    const size_t ps = (size_t)U * U;

    for (int kc = 0; kc < 32; kc++) {
        const float* ar = A + (size_t)arow * U + kc * 32 + kgof;
        float av[8];
        *(float4*)(av)     = *(const float4*)(ar);
        *(float4*)(av + 4) = *(const float4*)(ar + 4);
        ushortT thi[8], tmi[8], tlo[8];
        #pragma unroll
        for (int i = 0; i < 8; i++) split3(av[i], thi[i], tmi[i], tlo[i]);
        ((uint4*)Ahi)[tid]  = *(const uint4*)thi;
        ((uint4*)Amid)[tid] = *(const uint4*)tmi;
        ((uint4*)Alo)[tid]  = *(const uint4*)tlo;

        bf16x8 bh[2], bm[2], bl[2];
        #pragma unroll
        for (int j = 0; j < 2; j++) {
            if constexpr (PRESPLIT) {
                size_t fi = (((size_t)(nt0 + j) * 32 + kc) * 64 + lane) * 8;
                bh[j] = *(const bf16x8*)(Wp + fi);
                bm[j] = *(const bf16x8*)(Wp + ps + fi);
                bl[j] = *(const bf16x8*)(Wp + 2 * ps + fi);
            } else {
                const float* wp = W + (size_t)(kc * 32 + kfrag) * U + col0 + j * 16;
                ushortT whi[8], wmi[8], wlo[8];
                #pragma unroll
                for (int i = 0; i < 8; i++)
                    split3(wp[(size_t)i * U], whi[i], wmi[i], wlo[i]);
                bh[j] = *(const bf16x8*)whi;
                bm[j] = *(const bf16x8*)wmi;
                bl[j] = *(const bf16x8*)wlo;
            }
        }

        __syncthreads();
        #pragma unroll
        for (int mi = 0; mi < 4; mi++) {
            bf16x8 ah = *(const bf16x8*)(Ahi  + (mi * 64 + lane) * 8);
            bf16x8 am = *(const bf16x8*)(Amid + (mi * 64 + lane) * 8);
            bf16x8 al = *(const bf16x8*)(Alo  + (mi * 64 + lane) * 8);
            #pragma unroll
            for (int j = 0; j < 2; j++) {
                acc[j][mi] = __builtin_amdgcn_mfma_f32_16x16x32_bf16(ah, bh[j], acc[j][mi], 0, 0, 0);
                acc[j][mi] = __builtin_amdgcn_mfma_f32_16x16x32_bf16(am, bh[j], acc[j][mi], 0, 0, 0);
                acc[j][mi] = __builtin_amdgcn_mfma_f32_16x16x32_bf16(ah, bm[j], acc[j][mi], 0, 0, 0);
                acc[j][mi] = __builtin_amdgcn_mfma_f32_16x16x32_bf16(am, bm[j], acc[j][mi], 0, 0, 0);
                acc[j][mi] = __builtin_amdgcn_mfma_f32_16x16x32_bf16(al, bh[j], acc[j][mi], 0, 0, 0);
                acc[j][mi] = __builtin_amdgcn_mfma_f32_16x16x32_bf16(ah, bl[j], acc[j][mi], 0, 0, 0);
            }
        }
        __syncthreads();
    }

    #pragma unroll
    for (int mi = 0; mi < 4; mi++) {
        #pragma unroll
        for (int r = 0; r < 4; r++) {
            int m = row0 + mi * 16 + (lane >> 4) * 4 + r;
            #pragma unroll
            for (int j = 0; j < 2; j++)
                C[(size_t)m * U + col0 + j * 16] = acc[j][mi][r];
        }
    }
}

// ---------------------------------------------------------------------------
// xe[t] = emb[x[:,t]] @ gk[0:256,:]   grid (U3/64, T)
// ---------------------------------------------------------------------------
template<bool PRESPLIT>
__global__ __launch_bounds__(256) void gemm_xe(
    const int* __restrict__ x, const float* __restrict__ emb,
    const float* __restrict__ gk, const ushortT* __restrict__ gkp,
    float* __restrict__ xe)
{
    const int tid = threadIdx.x;
    const int lane = tid & 63;
    const int wave = tid >> 6;
    const int t = blockIdx.y;
    const int ntile = blockIdx.x * 4 + wave;
    const int col = ntile * 16 + (lane & 15);
    const int kfrag = (lane >> 4) * 8;

    __shared__ __align__(16) ushortT Ahi[2048];
    __shared__ __align__(16) ushortT Amid[2048];
    __shared__ __align__(16) ushortT Alo[2048];

    f32x4 acc[4] = {};
    const int b = (tid >> 6) * 16 + (tid & 15);
    const int tok = x[b * T + t];
    const int kgof = ((tid >> 4) & 3) * 8;
    const size_t ps = (size_t)KXM * U3;

    for (int kc = 0; kc < E / 32; kc++) {
        const float* ar = emb + (size_t)tok * E + kc * 32 + kgof;
        float av[8];
        *(float4*)(av)     = *(const float4*)(ar);
        *(float4*)(av + 4) = *(const float4*)(ar + 4);
        ushortT thi[8], tmi[8], tlo[8];
        #pragma unroll
        for (int i = 0; i < 8; i++) split3(av[i], thi[i], tmi[i], tlo[i]);
        ((uint4*)Ahi)[tid]  = *(const uint4*)thi;
        ((uint4*)Amid)[tid] = *(const uint4*)tmi;
        ((uint4*)Alo)[tid]  = *(const uint4*)tlo;

        bf16x8 bh, bm, bl;
        if constexpr (PRESPLIT) {
            size_t fi = (((size_t)ntile * 40 + kc) * 64 + lane) * 8;   // gk KCtot=40
            bh = *(const bf16x8*)(gkp + fi);
            bm = *(const bf16x8*)(gkp + ps + fi);
            bl = *(const bf16x8*)(gkp + 2 * ps + fi);
        } else {
            const float* wp = gk + (size_t)(kc * 32 + kfrag) * U3 + col;
            ushortT whi[8], wmi[8], wlo[8];
            #pragma unroll
            for (int i = 0; i < 8; i++)
                split3(wp[(size_t)i * U3], whi[i], wmi[i], wlo[i]);
            bh = *(const bf16x8*)whi;
            bm = *(const bf16x8*)wmi;
            bl = *(const bf16x8*)wlo;
        }

        __syncthreads();
        #pragma unroll
        for (int mi = 0; mi < 4; mi++) {
            bf16x8 ah = *(const bf16x8*)(Ahi  + (mi * 64 + lane) * 8);
            bf16x8 am = *(const bf16x8*)(Amid + (mi * 64 + lane) * 8);
            bf16x8 al = *(const bf16x8*)(Alo  + (mi * 64 + lane) * 8);
            acc[mi] = __builtin_amdgcn_mfma_f32_16x16x32_bf16(ah, bh, acc[mi], 0, 0, 0);
            acc[mi] = __builtin_amdgcn_mfma_f32_16x16x32_bf16(am, bh, acc[mi], 0, 0, 0);
            acc[mi] = __builtin_amdgcn_mfma_f32_16x16x32_bf16(ah, bm, acc[mi], 0, 0, 0);
            acc[mi] = __builtin_amdgcn_mfma_f32_16x16x32_bf16(am, bm, acc[mi], 0, 0, 0);
            acc[mi] = __builtin_amdgcn_mfma_f32_16x16x32_bf16(al, bh, acc[mi], 0, 0, 0);
            acc[mi] = __builtin_amdgcn_mfma_f32_16x16x32_bf16(ah, bl, acc[mi], 0, 0, 0);
        }
        __syncthreads();
    }

    #pragma unroll
    for (int mi = 0; mi < 4; mi++) {
        #pragma unroll
        for (int r = 0; r < 4; r++) {
            int m = mi * 16 + (lane >> 4) * 4 + r;
            xe[((size_t)t * 64 + m) * U3 + col] = acc[mi][r];
        }
    }
}

// ---------------------------------------------------------------------------
// fc GEMM v2: 2 n-tiles/wave, BK=64. grid = V/128 = 250 blocks.
// ---------------------------------------------------------------------------
__global__ __launch_bounds__(256) void gemm_fc2(
    const float* __restrict__ A, const ushortT* __restrict__ Wp,
    const float* __restrict__ bias, float* __restrict__ C)
{
    const int tid = threadIdx.x;
    const int lane = tid & 63;
    const int wave = tid >> 6;
    const int nt0 = blockIdx.x * 8 + wave * 2;
    const int col0 = nt0 * 16 + (lane & 15);

    __shared__ __align__(16) ushortT As[2][2048];

    f32x4 acc[2][4] = {};
    const int arow = (tid >> 6) * 16 + (tid & 15);
    const int kgof = ((tid >> 4) & 3) * 8;

    for (int it = 0; it < 16; it++) {
        #pragma unroll
        for (int c = 0; c < 2; c++) {
            const float* ar = A + (size_t)arow * U + (it * 2 + c) * 32 + kgof;
            float4 f0 = *(const float4*)(ar);
            float4 f1 = *(const float4*)(ar + 4);
            ushortT tmp[8] = { f2bf(f0.x), f2bf(f0.y), f2bf(f0.z), f2bf(f0.w),
                               f2bf(f1.x), f2bf(f1.y), f2bf(f1.z), f2bf(f1.w) };
            ((uint4*)As[c])[tid] = *(const uint4*)tmp;
        }
        bf16x8 b[2][2];
        #pragma unroll
        for (int c = 0; c < 2; c++)
            #pragma unroll
            for (int j = 0; j < 2; j++)
                b[c][j] = *(const bf16x8*)(Wp +
                    (((size_t)(nt0 + j) * 32 + it * 2 + c) * 64 + lane) * 8);
        __syncthreads();
        #pragma unroll
        for (int c = 0; c < 2; c++) {
            #pragma unroll
            for (int mi = 0; mi < 4; mi++) {
                bf16x8 a = *(const bf16x8*)(As[c] + (mi * 64 + lane) * 8);
                #pragma unroll
                for (int j = 0; j < 2; j++)
                    acc[j][mi] = __builtin_amdgcn_mfma_f32_16x16x32_bf16(a, b[c][j], acc[j][mi], 0, 0, 0);
            }
        }
        __syncthreads();
    }

    #pragma unroll
    for (int j = 0; j < 2; j++) {
        const float bv = bias[col0 + j * 16];
        #pragma unroll
        for (int mi = 0; mi < 4; mi++) {
            #pragma unroll
            for (int r = 0; r < 4; r++) {
                int m = mi * 16 + (lane >> 4) * 4 + r;
                C[(size_t)m * (T * V) + col0 + j * 16] = acc[j][mi][r] + bv;
            }
        }
    }
}

// ---------------------------------------------------------------------------
// elementwise kernels (unchanged from R5)
// ---------------------------------------------------------------------------
__global__ __launch_bounds__(256) void gates2(
    const float* __restrict__ xe_t, const float* __restrict__ xm_part,
    const float* __restrict__ hm_part, const float* __restrict__ gb,
    float* __restrict__ h, int use_xm)
{
    int idx = blockIdx.x * 256 + threadIdx.x;   // B*U
    int b = idx >> 10, u = idx & (U - 1);
    float xv[3], hv[3];
    #pragma unroll
    for (int g = 0; g < 3; g++) {
        int j = g * U + u;
        float xs = xe_t[(size_t)b * U3 + j] + gb[j];
        float hs = gb[U3 + j];
        if (use_xm) {
            #pragma unroll
            for (int p = 0; p < 4; p++)
                xs += xm_part[((size_t)p * 64 + b) * U3 + j];
        }
        #pragma unroll
        for (int p = 0; p < 4; p++)
            hs += hm_part[((size_t)p * 64 + b) * U3 + j];
        xv[g] = xs; hv[g] = hs;
    }
    float z = 1.f / (1.f + expf(-(xv[0] + hv[0])));
    float r = 1.f / (1.f + expf(-(xv[1] + hv[1])));
    float hh = tanhf(xv[2] + r * hv[2]);
    h[idx] = z * h[idx] + (1.f - z) * hh;
}

__global__ __launch_bounds__(256) void scores_kernel(
    const float* __restrict__ h, const float* __restrict__ keys,
    float* __restrict__ scores)
{
    int gw = blockIdx.x * 4 + (threadIdx.x >> 6);
    int lane = threadIdx.x & 63;
    int b = gw / S, s = gw - b * S;
    const float* kr = keys + ((size_t)b * S + s) * U;
    const float* hr = h + (size_t)b * U;
    float acc = 0.f;
    #pragma unroll
    for (int c = 0; c < 4; c++) {
        int off = c * 256 + lane * 4;
        float4 kv = *(const float4*)(kr + off);
        float4 hv = *(const float4*)(hr + off);
        acc += kv.x * hv.x + kv.y * hv.y + kv.z * hv.z + kv.w * hv.w;
    }
    #pragma unroll
    for (int off = 32; off > 0; off >>= 1) acc += __shfl_down(acc, off);
    if (lane == 0) scores[gw] = acc;
}

__global__ __launch_bounds__(256) void ctxcat_kernel(
    const float* __restrict__ scores, const float* __restrict__ memory,
    const float* __restrict__ h, float* __restrict__ cat2)
{
    const int b = blockIdx.x;
    const int u = blockIdx.y * 256 + threadIdx.x;
    __shared__ float p[S];
    __shared__ float pn[S];
    if (threadIdx.x < S) p[threadIdx.x] = scores[b * S + threadIdx.x];
    __syncthreads();
    float m = -1e30f;
    #pragma unroll 8
    for (int s = 0; s < S; s++) m = fmaxf(m, p[s]);
    float sum = 0.f;
    #pragma unroll 8
    for (int s = 0; s < S; s++) sum += expf(p[s] - m);
    if (threadIdx.x < S) pn[threadIdx.x] = expf(p[threadIdx.x] - m) / sum;
    __syncthreads();
    float acc = 0.f;
    #pragma unroll 8
    for (int s = 0; s < S; s++)
        acc += pn[s] * memory[((size_t)b * S + s) * U + u];
    cat2[(size_t)b * 2 * U + u] = h[(size_t)b * U + u];
    cat2[(size_t)b * 2 * U + U + u] = acc;
}

__global__ __launch_bounds__(256) void reduce_attnv(
    const float* __restrict__ attn_part, float* __restrict__ attnv)
{
    int idx = blockIdx.x * 256 + threadIdx.x;   // B*U
    float s = 0.f;
    #pragma unroll
    for (int p = 0; p < 8; p++) s += attn_part[(size_t)p * B * U + idx];
    attnv[idx] = s;
}

// ---------------------------------------------------------------------------
extern "C" void kernel_launch(void* const* d_in, const int* in_sizes, int n_in,
                              void* d_out, int out_size, void* d_ws, size_t ws_size,
                              hipStream_t stream)
{
    const int*   x      = (const int*)  d_in[0];
    const float* enc    = (const float*)d_in[1];
    const float* memory = (const float*)d_in[2];
    const float* emb    = (const float*)d_in[3];
    const float* gk     = (const float*)d_in[4];
    const float* grk    = (const float*)d_in[5];
    const float* gb     = (const float*)d_in[6];
    const float* memW   = (const float*)d_in[7];
    const float* attnW  = (const float*)d_in[8];
    const float* fcW    = (const float*)d_in[9];
    const float* fcb    = (const float*)d_in[10];
    float* out = (float*)d_out;

    char* p = (char*)d_ws;
    auto alloc = [&](size_t bytes) { char* r = p; p += (bytes + 255) & ~(size_t)255; return r; };
    // common (≈111 MB, R5-proven)
    ushortT* fcWp     = (ushortT*)alloc((size_t)U * V * 2);
    float*   keys     = (float*)  alloc((size_t)B * S * U * 4);
    float*   xe       = (float*)  alloc((size_t)T * B * U3 * 4);
    float*   xm_part  = (float*)  alloc((size_t)4 * B * U3 * 4);
    float*   hm_part  = (float*)  alloc((size_t)4 * B * U3 * 4);
    float*   attn_part= (float*)  alloc((size_t)8 * B * U * 4);
    float*   h        = (float*)  alloc((size_t)B * U * 4);
    float*   attnv    = (float*)  alloc((size_t)B * U * 4);
    float*   cat2     = (float*)  alloc((size_t)B * 2 * U * 4);
    float*   scores   = (float*)  alloc((size_t)B * S * 4);
    // pre-split weight planes (+61 MB)
    ushortT* gkp      = (ushortT*)alloc((size_t)KXM * U3 * 2 * 3);
    ushortT* grkp     = (ushortT*)alloc((size_t)U * U3 * 2 * 3);
    ushortT* awp      = (ushortT*)alloc((size_t)2 * U * U * 2 * 3);
    ushortT* mwp      = (ushortT*)alloc((size_t)U * U * 2 * 3);
    const bool PS = (size_t)(p - (char*)d_ws) <= ws_size;

    dim3 blk(256);

    if (PS) {
        pack_w3<<<(size_t)KXM * U3 / 8 / 256, blk, 0, stream>>>(gk, gkp, U3, KXM);
        pack_w3<<<(size_t)U * U3 / 8 / 256, blk, 0, stream>>>(grk, grkp, U3, U);
        pack_w3<<<(size_t)2 * U * U / 8 / 256, blk, 0, stream>>>(attnW, awp, U, 2 * U);
        pack_w3<<<(size_t)U * U / 8 / 256, blk, 0, stream>>>(memW, mwp, U, U);
    }
    pack_w<<<(size_t)U * V / 8 / 256, blk, 0, stream>>>(fcW, fcWp, V, U);
    (void)hipMemcpyAsync(h, enc, (size_t)B * U * sizeof(float),
                         hipMemcpyDeviceToDevice, stream);

    if (PS) gemm_xe<true><<<dim3(U3 / 64, T), blk, 0, stream>>>(x, emb, gk, gkp, xe);
    else    gemm_xe<false><<<dim3(U3 / 64, T), blk, 0, stream>>>(x, emb, gk, gkp, xe);

    if (PS) gemm_keys<true><<<dim3(U / 128, B * S / 64), blk, 0, stream>>>(memory, memW, mwp, keys);
    else    gemm_keys<false><<<dim3(U / 128, B * S / 64), blk, 0, stream>>>(memory, memW, mwp, keys);

    GemmJob job_hm = { h,     grk,   grkp, (size_t)U * U3,   0, 32, hm_part,   U };
    GemmJob job_xm = { attnv, gk,    gkp,  (size_t)KXM * U3, 8, 40, xm_part,   U };
    GemmJob job_at = { cat2,  attnW, awp,  (size_t)2 * U * U, 0, 64, attn_part, 2 * U };

    for (int t = 0; t < T; t++) {
        dim3 g1(U3 / 64, 4, t > 0 ? 2 : 1);
        if (PS) gemm6_ks2<true><<<g1, blk, 0, stream>>>(job_hm, job_xm, U3, 8);
        else    gemm6_ks2<false><<<g1, blk, 0, stream>>>(job_hm, job_xm, U3, 8);
        gates2<<<B * U / 256, blk, 0, stream>>>(
            xe + (size_t)t * B * U3, xm_part, hm_part, gb, h, t > 0 ? 1 : 0);
        scores_kernel<<<B * S / 4, blk, 0, stream>>>(h, keys, scores);
        ctxcat_kernel<<<dim3(B, U / 256), blk, 0, stream>>>(scores, memory, h, cat2);
        dim3 g2(U / 64, 8, 1);
        if (PS) gemm6_ks2<true><<<g2, blk, 0, stream>>>(job_at, job_at, U, 8);
        else    gemm6_ks2<false><<<g2, blk, 0, stream>>>(job_at, job_at, U, 8);
        reduce_attnv<<<B * U / 256, blk, 0, stream>>>(attn_part, attnv);
        gemm_fc2<<<V / 128, blk, 0, stream>>>(
            attnv, fcWp, fcb, out + (size_t)t * V);
    }
}

// Round 8
// 1505.721 us; speedup vs baseline: 6.3523x; 1.0108x over previous
//
#include <hip/hip_runtime.h>
#include <hip/hip_bf16.h>
#include <math.h>

#define B 64
#define T 19
#define S 80
#define V 32000
#define E 256
#define U 1024
#define U3 (3*U)        // 3072
#define KXM (E+U)       // 1280

typedef unsigned short ushortT;
typedef __attribute__((ext_vector_type(8))) __bf16 bf16x8;
typedef __attribute__((ext_vector_type(4))) float f32x4;

__device__ __forceinline__ ushortT f2bf(float f) {
    unsigned int u = __float_as_uint(f);
    u = (u + 0x7FFF + ((u >> 16) & 1)) >> 16;   // RNE
    return (ushortT)u;
}
__device__ __forceinline__ float bf2f(ushortT u) {
    return __uint_as_float(((unsigned int)u) << 16);
}
__device__ __forceinline__ void split3(float v, ushortT& hi, ushortT& mid, ushortT& lo) {
    hi = f2bf(v);
    float r1 = v - bf2f(hi);
    mid = f2bf(r1);
    float r2 = r1 - bf2f(mid);
    lo = f2bf(r2);
}

// ---------------------------------------------------------------------------
// Pre-split weight pack: W fp32 [K][N] -> 3 bf16 planes in MFMA fragment order
// ---------------------------------------------------------------------------
__global__ __launch_bounds__(256) void pack_w3(
    const float* __restrict__ W, ushortT* __restrict__ Wp, int N, int K)
{
    int idx = blockIdx.x * 256 + threadIdx.x;
    int lane = idx & 63;
    int t = idx >> 6;
    int KC = K >> 5;
    int ntile = t / KC, kc = t - ntile * KC;
    int col = ntile * 16 + (lane & 15);
    int krow = kc * 32 + (lane >> 4) * 8;
    ushortT hi[8], mi[8], lo[8];
    #pragma unroll
    for (int i = 0; i < 8; i++)
        split3(W[(size_t)(krow + i) * N + col], hi[i], mi[i], lo[i]);
    size_t ps = (size_t)K * N;
    *(uint4*)(Wp + (size_t)idx * 8)          = *(uint4*)hi;
    *(uint4*)(Wp + ps + (size_t)idx * 8)     = *(uint4*)mi;
    *(uint4*)(Wp + 2 * ps + (size_t)idx * 8) = *(uint4*)lo;
}

// fc pack (single bf16, proven)
__global__ __launch_bounds__(256) void pack_w(
    const float* __restrict__ W, ushortT* __restrict__ Wp, int N, int K)
{
    int idx = blockIdx.x * 256 + threadIdx.x;
    int lane = idx & 63;
    int t = idx >> 6;
    int KC = K >> 5;
    int ntile = t / KC, kc = t - ntile * KC;
    int col = ntile * 16 + (lane & 15);
    int krow = kc * 32 + (lane >> 4) * 8;
    ushortT tmp[8];
    #pragma unroll
    for (int i = 0; i < 8; i++)
        tmp[i] = f2bf(W[(size_t)(krow + i) * N + col]);
    *(uint4*)(Wp + (size_t)idx * 8) = *(uint4*)tmp;
}

// ---------------------------------------------------------------------------
// Unified per-step split6 GEMM with K-split and 2-job fusion (blockIdx.z).
// ---------------------------------------------------------------------------
struct GemmJob {
    const float*   A;
    const float*   W;
    const ushortT* Wp;
    unsigned long long ps;
    int kc_base;
    int KCtot;
    float* Cpart;
    int lda;
};

template<bool PRESPLIT>
__global__ __launch_bounds__(256) void gemm6_ks2(
    GemmJob j0, GemmJob j1, int N, int nkc)
{
    const int tid = threadIdx.x;
    const int lane = tid & 63;
    const int wave = tid >> 6;
    const GemmJob J = blockIdx.z ? j1 : j0;
    const int ks = blockIdx.y;
    const int ntile = blockIdx.x * 4 + wave;
    const int col = ntile * 16 + (lane & 15);
    const int kfrag = (lane >> 4) * 8;

    __shared__ __align__(16) ushortT Ahi[2048];
    __shared__ __align__(16) ushortT Amid[2048];
    __shared__ __align__(16) ushortT Alo[2048];

    f32x4 acc[4] = {};
    const int arow = (tid >> 6) * 16 + (tid & 15);
    const int kgof = ((tid >> 4) & 3) * 8;

    for (int c = 0; c < nkc; c++) {
        const int kc = ks * nkc + c;
        const float* ar = J.A + (size_t)arow * J.lda + kc * 32 + kgof;
        float av[8];
        *(float4*)(av)     = *(const float4*)(ar);
        *(float4*)(av + 4) = *(const float4*)(ar + 4);
        ushortT thi[8], tmi[8], tlo[8];
        #pragma unroll
        for (int i = 0; i < 8; i++) split3(av[i], thi[i], tmi[i], tlo[i]);
        ((uint4*)Ahi)[tid]  = *(const uint4*)thi;
        ((uint4*)Amid)[tid] = *(const uint4*)tmi;
        ((uint4*)Alo)[tid]  = *(const uint4*)tlo;

        bf16x8 bh, bm, bl;
        if constexpr (PRESPLIT) {
            size_t fi = (((size_t)ntile * J.KCtot + (J.kc_base + kc)) * 64 + lane) * 8;
            bh = *(const bf16x8*)(J.Wp + fi);
            bm = *(const bf16x8*)(J.Wp + J.ps + fi);
            bl = *(const bf16x8*)(J.Wp + 2 * J.ps + fi);
        } else {
            const float* wp = J.W + (size_t)((J.kc_base + kc) * 32 + kfrag) * N + col;
            ushortT whi[8], wmi[8], wlo[8];
            #pragma unroll
            for (int i = 0; i < 8; i++)
                split3(wp[(size_t)i * N], whi[i], wmi[i], wlo[i]);
            bh = *(const bf16x8*)whi;
            bm = *(const bf16x8*)wmi;
            bl = *(const bf16x8*)wlo;
        }

        __syncthreads();
        #pragma unroll
        for (int mi = 0; mi < 4; mi++) {
            bf16x8 ah = *(const bf16x8*)(Ahi  + (mi * 64 + lane) * 8);
            bf16x8 am = *(const bf16x8*)(Amid + (mi * 64 + lane) * 8);
            bf16x8 al = *(const bf16x8*)(Alo  + (mi * 64 + lane) * 8);
            acc[mi] = __builtin_amdgcn_mfma_f32_16x16x32_bf16(ah, bh, acc[mi], 0, 0, 0);
            acc[mi] = __builtin_amdgcn_mfma_f32_16x16x32_bf16(am, bh, acc[mi], 0, 0, 0);
            acc[mi] = __builtin_amdgcn_mfma_f32_16x16x32_bf16(ah, bm, acc[mi], 0, 0, 0);
            acc[mi] = __builtin_amdgcn_mfma_f32_16x16x32_bf16(am, bm, acc[mi], 0, 0, 0);
            acc[mi] = __builtin_amdgcn_mfma_f32_16x16x32_bf16(al, bh, acc[mi], 0, 0, 0);
            acc[mi] = __builtin_amdgcn_mfma_f32_16x16x32_bf16(ah, bl, acc[mi], 0, 0, 0);
        }
        __syncthreads();
    }

    float* cp = J.Cpart + (size_t)ks * 64 * N;
    #pragma unroll
    for (int mi = 0; mi < 4; mi++) {
        #pragma unroll
        for (int r = 0; r < 4; r++) {
            int m = mi * 16 + (lane >> 4) * 4 + r;
            cp[(size_t)m * N + col] = acc[mi][r];
        }
    }
}

// ---------------------------------------------------------------------------
// keys = memory @ mem_W: 2 n-tiles per wave, grid (U/128, B*S/64).
// ---------------------------------------------------------------------------
template<bool PRESPLIT>
__global__ __launch_bounds__(256) void gemm_keys(
    const float* __restrict__ A, const float* __restrict__ W,
    const ushortT* __restrict__ Wp, float* __restrict__ C)
{
    const int tid = threadIdx.x;
    const int lane = tid & 63;
    const int wave = tid >> 6;
    const int row0 = blockIdx.y * 64;
    const int nt0 = blockIdx.x * 8 + wave * 2;
    const int col0 = nt0 * 16 + (lane & 15);
    const int kfrag = (lane >> 4) * 8;

    __shared__ __align__(16) ushortT Ahi[2048];
    __shared__ __align__(16) ushortT Amid[2048];
    __shared__ __align__(16) ushortT Alo[2048];

    f32x4 acc[2][4] = {};
    const int arow = row0 + (tid >> 6) * 16 + (tid & 15);
    const int kgof = ((tid >> 4) & 3) * 8;
    const size_t ps = (size_t)U * U;

    for (int kc = 0; kc < 32; kc++) {
        const float* ar = A + (size_t)arow * U + kc * 32 + kgof;
        float av[8];
        *(float4*)(av)     = *(const float4*)(ar);
        *(float4*)(av + 4) = *(const float4*)(ar + 4);
        ushortT thi[8], tmi[8], tlo[8];
        #pragma unroll
        for (int i = 0; i < 8; i++) split3(av[i], thi[i], tmi[i], tlo[i]);
        ((uint4*)Ahi)[tid]  = *(const uint4*)thi;
        ((uint4*)Amid)[tid] = *(const uint4*)tmi;
        ((uint4*)Alo)[tid]  = *(const uint4*)tlo;

        bf16x8 bh[2], bm[2], bl[2];
        #pragma unroll
        for (int j = 0; j < 2; j++) {
            if constexpr (PRESPLIT) {
                size_t fi = (((size_t)(nt0 + j) * 32 + kc) * 64 + lane) * 8;
                bh[j] = *(const bf16x8*)(Wp + fi);
                bm[j] = *(const bf16x8*)(Wp + ps + fi);
                bl[j] = *(const bf16x8*)(Wp + 2 * ps + fi);
            } else {
                const float* wp = W + (size_t)(kc * 32 + kfrag) * U + col0 + j * 16;
                ushortT whi[8], wmi[8], wlo[8];
                #pragma unroll
                for (int i = 0; i < 8; i++)
                    split3(wp[(size_t)i * U], whi[i], wmi[i], wlo[i]);
                bh[j] = *(const bf16x8*)whi;
                bm[j] = *(const bf16x8*)wmi;
                bl[j] = *(const bf16x8*)wlo;
            }
        }

        __syncthreads();
        #pragma unroll
        for (int mi = 0; mi < 4; mi++) {
            bf16x8 ah = *(const bf16x8*)(Ahi  + (mi * 64 + lane) * 8);
            bf16x8 am = *(const bf16x8*)(Amid + (mi * 64 + lane) * 8);
            bf16x8 al = *(const bf16x8*)(Alo  + (mi * 64 + lane) * 8);
            #pragma unroll
            for (int j = 0; j < 2; j++) {
                acc[j][mi] = __builtin_amdgcn_mfma_f32_16x16x32_bf16(ah, bh[j], acc[j][mi], 0, 0, 0);
                acc[j][mi] = __builtin_amdgcn_mfma_f32_16x16x32_bf16(am, bh[j], acc[j][mi], 0, 0, 0);
                acc[j][mi] = __builtin_amdgcn_mfma_f32_16x16x32_bf16(ah, bm[j], acc[j][mi], 0, 0, 0);
                acc[j][mi] = __builtin_amdgcn_mfma_f32_16x16x32_bf16(am, bm[j], acc[j][mi], 0, 0, 0);
                acc[j][mi] = __builtin_amdgcn_mfma_f32_16x16x32_bf16(al, bh[j], acc[j][mi], 0, 0, 0);
                acc[j][mi] = __builtin_amdgcn_mfma_f32_16x16x32_bf16(ah, bl[j], acc[j][mi], 0, 0, 0);
            }
        }
        __syncthreads();
    }

    #pragma unroll
    for (int mi = 0; mi < 4; mi++) {
        #pragma unroll
        for (int r = 0; r < 4; r++) {
            int m = row0 + mi * 16 + (lane >> 4) * 4 + r;
            #pragma unroll
            for (int j = 0; j < 2; j++)
                C[(size_t)m * U + col0 + j * 16] = acc[j][mi][r];
        }
    }
}

// ---------------------------------------------------------------------------
// xe[t] = emb[x[:,t]] @ gk[0:256,:]   grid (U3/64, T)
// ---------------------------------------------------------------------------
template<bool PRESPLIT>
__global__ __launch_bounds__(256) void gemm_xe(
    const int* __restrict__ x, const float* __restrict__ emb,
    const float* __restrict__ gk, const ushortT* __restrict__ gkp,
    float* __restrict__ xe)
{
    const int tid = threadIdx.x;
    const int lane = tid & 63;
    const int wave = tid >> 6;
    const int t = blockIdx.y;
    const int ntile = blockIdx.x * 4 + wave;
    const int col = ntile * 16 + (lane & 15);
    const int kfrag = (lane >> 4) * 8;

    __shared__ __align__(16) ushortT Ahi[2048];
    __shared__ __align__(16) ushortT Amid[2048];
    __shared__ __align__(16) ushortT Alo[2048];

    f32x4 acc[4] = {};
    const int b = (tid >> 6) * 16 + (tid & 15);
    const int tok = x[b * T + t];
    const int kgof = ((tid >> 4) & 3) * 8;
    const size_t ps = (size_t)KXM * U3;

    for (int kc = 0; kc < E / 32; kc++) {
        const float* ar = emb + (size_t)tok * E + kc * 32 + kgof;
        float av[8];
        *(float4*)(av)     = *(const float4*)(ar);
        *(float4*)(av + 4) = *(const float4*)(ar + 4);
        ushortT thi[8], tmi[8], tlo[8];
        #pragma unroll
        for (int i = 0; i < 8; i++) split3(av[i], thi[i], tmi[i], tlo[i]);
        ((uint4*)Ahi)[tid]  = *(const uint4*)thi;
        ((uint4*)Amid)[tid] = *(const uint4*)tmi;
        ((uint4*)Alo)[tid]  = *(const uint4*)tlo;

        bf16x8 bh, bm, bl;
        if constexpr (PRESPLIT) {
            size_t fi = (((size_t)ntile * 40 + kc) * 64 + lane) * 8;   // gk KCtot=40
            bh = *(const bf16x8*)(gkp + fi);
            bm = *(const bf16x8*)(gkp + ps + fi);
            bl = *(const bf16x8*)(gkp + 2 * ps + fi);
        } else {
            const float* wp = gk + (size_t)(kc * 32 + kfrag) * U3 + col;
            ushortT whi[8], wmi[8], wlo[8];
            #pragma unroll
            for (int i = 0; i < 8; i++)
                split3(wp[(size_t)i * U3], whi[i], wmi[i], wlo[i]);
            bh = *(const bf16x8*)whi;
            bm = *(const bf16x8*)wmi;
            bl = *(const bf16x8*)wlo;
        }

        __syncthreads();
        #pragma unroll
        for (int mi = 0; mi < 4; mi++) {
            bf16x8 ah = *(const bf16x8*)(Ahi  + (mi * 64 + lane) * 8);
            bf16x8 am = *(const bf16x8*)(Amid + (mi * 64 + lane) * 8);
            bf16x8 al = *(const bf16x8*)(Alo  + (mi * 64 + lane) * 8);
            acc[mi] = __builtin_amdgcn_mfma_f32_16x16x32_bf16(ah, bh, acc[mi], 0, 0, 0);
            acc[mi] = __builtin_amdgcn_mfma_f32_16x16x32_bf16(am, bh, acc[mi], 0, 0, 0);
            acc[mi] = __builtin_amdgcn_mfma_f32_16x16x32_bf16(ah, bm, acc[mi], 0, 0, 0);
            acc[mi] = __builtin_amdgcn_mfma_f32_16x16x32_bf16(am, bm, acc[mi], 0, 0, 0);
            acc[mi] = __builtin_amdgcn_mfma_f32_16x16x32_bf16(al, bh, acc[mi], 0, 0, 0);
            acc[mi] = __builtin_amdgcn_mfma_f32_16x16x32_bf16(ah, bl, acc[mi], 0, 0, 0);
        }
        __syncthreads();
    }

    #pragma unroll
    for (int mi = 0; mi < 4; mi++) {
        #pragma unroll
        for (int r = 0; r < 4; r++) {
            int m = mi * 16 + (lane >> 4) * 4 + r;
            xe[((size_t)t * 64 + m) * U3 + col] = acc[mi][r];
        }
    }
}

// ---------------------------------------------------------------------------
// Batched fc GEMM over all T steps: A = attnv_all [T*64][U].
// grid (V/128, T); same per-t math as R7's gemm_fc2 (bit-identical logits).
// ---------------------------------------------------------------------------
__global__ __launch_bounds__(256) void gemm_fcB(
    const float* __restrict__ A, const ushortT* __restrict__ Wp,
    const float* __restrict__ bias, float* __restrict__ C)
{
    const int tid = threadIdx.x;
    const int lane = tid & 63;
    const int wave = tid >> 6;
    const int tg = blockIdx.y;
    const int nt0 = blockIdx.x * 8 + wave * 2;
    const int col0 = nt0 * 16 + (lane & 15);

    __shared__ __align__(16) ushortT As[2][2048];

    f32x4 acc[2][4] = {};
    const int arow = (tid >> 6) * 16 + (tid & 15);
    const float* At = A + (size_t)tg * 64 * U;
    float* Ct = C + (size_t)tg * V;
    const int kgof = ((tid >> 4) & 3) * 8;

    for (int it = 0; it < 16; it++) {
        #pragma unroll
        for (int c = 0; c < 2; c++) {
            const float* ar = At + (size_t)arow * U + (it * 2 + c) * 32 + kgof;
            float4 f0 = *(const float4*)(ar);
            float4 f1 = *(const float4*)(ar + 4);
            ushortT tmp[8] = { f2bf(f0.x), f2bf(f0.y), f2bf(f0.z), f2bf(f0.w),
                               f2bf(f1.x), f2bf(f1.y), f2bf(f1.z), f2bf(f1.w) };
            ((uint4*)As[c])[tid] = *(const uint4*)tmp;
        }
        bf16x8 b[2][2];
        #pragma unroll
        for (int c = 0; c < 2; c++)
            #pragma unroll
            for (int j = 0; j < 2; j++)
                b[c][j] = *(const bf16x8*)(Wp +
                    (((size_t)(nt0 + j) * 32 + it * 2 + c) * 64 + lane) * 8);
        __syncthreads();
        #pragma unroll
        for (int c = 0; c < 2; c++) {
            #pragma unroll
            for (int mi = 0; mi < 4; mi++) {
                bf16x8 a = *(const bf16x8*)(As[c] + (mi * 64 + lane) * 8);
                #pragma unroll
                for (int j = 0; j < 2; j++)
                    acc[j][mi] = __builtin_amdgcn_mfma_f32_16x16x32_bf16(a, b[c][j], acc[j][mi], 0, 0, 0);
            }
        }
        __syncthreads();
    }

    #pragma unroll
    for (int j = 0; j < 2; j++) {
        const float bv = bias[col0 + j * 16];
        #pragma unroll
        for (int mi = 0; mi < 4; mi++) {
            #pragma unroll
            for (int r = 0; r < 4; r++) {
                int m = mi * 16 + (lane >> 4) * 4 + r;
                Ct[(size_t)m * (T * V) + col0 + j * 16] = acc[j][mi][r] + bv;
            }
        }
    }
}

// ---------------------------------------------------------------------------
// Fused GRU gates + scores: one block per batch b.
// gates math identical to R7 gates2; scores math identical to R7 scores_kernel.
// ---------------------------------------------------------------------------
__global__ __launch_bounds__(256) void gs_fused(
    const float* __restrict__ xe_t, const float* __restrict__ xm_part,
    const float* __restrict__ hm_part, const float* __restrict__ gb,
    const float* __restrict__ keys, float* __restrict__ h,
    float* __restrict__ cat2, float* __restrict__ scores, int use_xm)
{
    const int b = blockIdx.x;
    const int tid = threadIdx.x;
    __shared__ __align__(16) float hs[U];

    #pragma unroll
    for (int k = 0; k < 4; k++) {
        int u = k * 256 + tid;
        float xv[3], hv[3];
        #pragma unroll
        for (int g = 0; g < 3; g++) {
            int j = g * U + u;
            float xs = xe_t[(size_t)b * U3 + j] + gb[j];
            float hsum = gb[U3 + j];
            if (use_xm) {
                #pragma unroll
                for (int p = 0; p < 4; p++)
                    xs += xm_part[((size_t)p * 64 + b) * U3 + j];
            }
            #pragma unroll
            for (int p = 0; p < 4; p++)
                hsum += hm_part[((size_t)p * 64 + b) * U3 + j];
            xv[g] = xs; hv[g] = hsum;
        }
        float z = 1.f / (1.f + expf(-(xv[0] + hv[0])));
        float r = 1.f / (1.f + expf(-(xv[1] + hv[1])));
        float hh = tanhf(xv[2] + r * hv[2]);
        float hn = z * h[(size_t)b * U + u] + (1.f - z) * hh;
        h[(size_t)b * U + u] = hn;
        hs[u] = hn;
        cat2[(size_t)b * 2 * U + u] = hn;
    }
    __syncthreads();

    const int wave = tid >> 6, lane = tid & 63;
    for (int s = wave; s < S; s += 4) {
        const float* kr = keys + ((size_t)b * S + s) * U;
        float acc = 0.f;
        #pragma unroll
        for (int c = 0; c < 4; c++) {
            int off = c * 256 + lane * 4;
            float4 kv = *(const float4*)(kr + off);
            float4 hv4 = *(const float4*)(hs + off);
            acc += kv.x * hv4.x + kv.y * hv4.y + kv.z * hv4.z + kv.w * hv4.w;
        }
        #pragma unroll
        for (int off = 32; off > 0; off >>= 1) acc += __shfl_down(acc, off);
        if (lane == 0) scores[b * S + s] = acc;
    }
}

// softmax + context (cat2 second half only); grid (B, U/256)
__global__ __launch_bounds__(256) void ctxcat2_kernel(
    const float* __restrict__ scores, const float* __restrict__ memory,
    float* __restrict__ cat2)
{
    const int b = blockIdx.x;
    const int u = blockIdx.y * 256 + threadIdx.x;
    __shared__ float p[S];
    __shared__ float pn[S];
    if (threadIdx.x < S) p[threadIdx.x] = scores[b * S + threadIdx.x];
    __syncthreads();
    float m = -1e30f;
    #pragma unroll 8
    for (int s = 0; s < S; s++) m = fmaxf(m, p[s]);
    float sum = 0.f;
    #pragma unroll 8
    for (int s = 0; s < S; s++) sum += expf(p[s] - m);
    if (threadIdx.x < S) pn[threadIdx.x] = expf(p[threadIdx.x] - m) / sum;
    __syncthreads();
    float acc = 0.f;
    #pragma unroll 8
    for (int s = 0; s < S; s++)
        acc += pn[s] * memory[((size_t)b * S + s) * U + u];
    cat2[(size_t)b * 2 * U + U + u] = acc;
}

// attnv_all[t] = sum8(attn_part)
__global__ __launch_bounds__(256) void reduce_attnv(
    const float* __restrict__ attn_part, float* __restrict__ dst)
{
    int idx = blockIdx.x * 256 + threadIdx.x;   // B*U
    float s = 0.f;
    #pragma unroll
    for (int p = 0; p < 8; p++) s += attn_part[(size_t)p * B * U + idx];
    dst[idx] = s;
}

// ---------------------------------------------------------------------------
extern "C" void kernel_launch(void* const* d_in, const int* in_sizes, int n_in,
                              void* d_out, int out_size, void* d_ws, size_t ws_size,
                              hipStream_t stream)
{
    const int*   x      = (const int*)  d_in[0];
    const float* enc    = (const float*)d_in[1];
    const float* memory = (const float*)d_in[2];
    const float* emb    = (const float*)d_in[3];
    const float* gk     = (const float*)d_in[4];
    const float* grk    = (const float*)d_in[5];
    const float* gb     = (const float*)d_in[6];
    const float* memW   = (const float*)d_in[7];
    const float* attnW  = (const float*)d_in[8];
    const float* fcW    = (const float*)d_in[9];
    const float* fcb    = (const float*)d_in[10];
    float* out = (float*)d_out;

    char* p = (char*)d_ws;
    auto alloc = [&](size_t bytes) { char* r = p; p += (bytes + 255) & ~(size_t)255; return r; };
    ushortT* fcWp      = (ushortT*)alloc((size_t)U * V * 2);
    float*   keys      = (float*)  alloc((size_t)B * S * U * 4);
    float*   xe        = (float*)  alloc((size_t)T * B * U3 * 4);
    float*   xm_part   = (float*)  alloc((size_t)4 * B * U3 * 4);
    float*   hm_part   = (float*)  alloc((size_t)4 * B * U3 * 4);
    float*   attn_part = (float*)  alloc((size_t)8 * B * U * 4);
    float*   h         = (float*)  alloc((size_t)B * U * 4);
    float*   attnv_all = (float*)  alloc((size_t)T * B * U * 4);
    float*   cat2      = (float*)  alloc((size_t)B * 2 * U * 4);
    float*   scores    = (float*)  alloc((size_t)B * S * 4);
    ushortT* gkp       = (ushortT*)alloc((size_t)KXM * U3 * 2 * 3);
    ushortT* grkp      = (ushortT*)alloc((size_t)U * U3 * 2 * 3);
    ushortT* awp       = (ushortT*)alloc((size_t)2 * U * U * 2 * 3);
    ushortT* mwp       = (ushortT*)alloc((size_t)U * U * 2 * 3);
    const bool PS = (size_t)(p - (char*)d_ws) <= ws_size;

    dim3 blk(256);

    if (PS) {
        pack_w3<<<(size_t)KXM * U3 / 8 / 256, blk, 0, stream>>>(gk, gkp, U3, KXM);
        pack_w3<<<(size_t)U * U3 / 8 / 256, blk, 0, stream>>>(grk, grkp, U3, U);
        pack_w3<<<(size_t)2 * U * U / 8 / 256, blk, 0, stream>>>(attnW, awp, U, 2 * U);
        pack_w3<<<(size_t)U * U / 8 / 256, blk, 0, stream>>>(memW, mwp, U, U);
    }
    pack_w<<<(size_t)U * V / 8 / 256, blk, 0, stream>>>(fcW, fcWp, V, U);
    (void)hipMemcpyAsync(h, enc, (size_t)B * U * sizeof(float),
                         hipMemcpyDeviceToDevice, stream);

    if (PS) gemm_xe<true><<<dim3(U3 / 64, T), blk, 0, stream>>>(x, emb, gk, gkp, xe);
    else    gemm_xe<false><<<dim3(U3 / 64, T), blk, 0, stream>>>(x, emb, gk, gkp, xe);

    if (PS) gemm_keys<true><<<dim3(U / 128, B * S / 64), blk, 0, stream>>>(memory, memW, mwp, keys);
    else    gemm_keys<false><<<dim3(U / 128, B * S / 64), blk, 0, stream>>>(memory, memW, mwp, keys);

    GemmJob job_hm = { h,    grk,   grkp, (size_t)U * U3,    0, 32, hm_part,   U };
    GemmJob job_at = { cat2, attnW, awp,  (size_t)2 * U * U, 0, 64, attn_part, 2 * U };

    for (int t = 0; t < T; t++) {
        GemmJob job_xm = { attnv_all + (size_t)(t - 1) * B * U, gk, gkp,
                           (size_t)KXM * U3, 8, 40, xm_part, U };
        dim3 g1(U3 / 64, 4, t > 0 ? 2 : 1);
        if (PS) gemm6_ks2<true><<<g1, blk, 0, stream>>>(job_hm, job_xm, U3, 8);
        else    gemm6_ks2<false><<<g1, blk, 0, stream>>>(job_hm, job_xm, U3, 8);
        gs_fused<<<B, blk, 0, stream>>>(
            xe + (size_t)t * B * U3, xm_part, hm_part, gb, keys, h, cat2,
            scores, t > 0 ? 1 : 0);
        ctxcat2_kernel<<<dim3(B, U / 256), blk, 0, stream>>>(scores, memory, cat2);
        dim3 g2(U / 64, 8, 1);
        if (PS) gemm6_ks2<true><<<g2, blk, 0, stream>>>(job_at, job_at, U, 8);
        else    gemm6_ks2<false><<<g2, blk, 0, stream>>>(job_at, job_at, U, 8);
        reduce_attnv<<<B * U / 256, blk, 0, stream>>>(
            attn_part, attnv_all + (size_t)t * B * U);
    }

    // all logits at once: [T*64, U] @ [U, V] + fcb
    gemm_fcB<<<dim3(V / 128, T), blk, 0, stream>>>(attnv_all, fcWp, fcb, out);
}